// Round 3
// baseline (633.815 us; speedup 1.0000x reference)
//
#include <hip/hip_runtime.h>
#include <hip/hip_bf16.h>

#define N_NODES 100000
#define D_IN 128
#define D_H 256
#define D_E 64
#define MT 32        // nodes per GEMM block
#define SCAN_B 1024  // scan block size
#define BSHIFT 6                                   // 64 nodes per bucket
#define NBUCK ((N_NODES + 63) >> BSHIFT)           // 1563

typedef __attribute__((ext_vector_type(8))) short short8;
typedef __attribute__((ext_vector_type(4))) float floatx4;

__device__ inline unsigned short f2bf(float f) {
    union { float f; unsigned u; } v; v.f = f;
    unsigned r = v.u + 0x7FFF + ((v.u >> 16) & 1);
    return (unsigned short)(r >> 16);
}
__device__ inline unsigned f2bf2(float a, float b) {
    return (unsigned)f2bf(a) | ((unsigned)f2bf(b) << 16);
}
__device__ inline float2 bf2f2(unsigned v) {
    union { unsigned u; float f; } lo, hi;
    lo.u = v << 16;
    hi.u = v & 0xffff0000u;
    return make_float2(lo.f, hi.f);  // .x = lower-address bf16
}

#define MFMA16(a, b, c) __builtin_amdgcn_mfma_f32_16x16x32_bf16((a), (b), (c), 0, 0, 0)

// ---------------- weight pre-pack to bf16, SWIZZLED to MFMA fragment order ----
__global__ void convert_weights(const float* __restrict__ Wl1, const float* __restrict__ Wr1,
                                const float* __restrict__ Wl2, const float* __restrict__ Wr2,
                                const float* __restrict__ fc1W, const float* __restrict__ fc2W,
                                unsigned short* __restrict__ W1s, unsigned short* __restrict__ W2s,
                                unsigned short* __restrict__ F1s, unsigned short* __restrict__ F2s) {
    int idx = blockIdx.x * blockDim.x + threadIdx.x;
    if (idx < 65536) {
        int out = idx >> 8, k = idx & 255;
        float v = (k < 128) ? Wl1[out * 128 + k] : Wr1[out * 128 + (k - 128)];
        int ks = k >> 5, quad = (k >> 3) & 3, e = k & 7, col = out & 15;
        int g = (out >> 4) * 8 + ks;
        W1s[(g * 64 + quad * 16 + col) * 8 + e] = f2bf(v);
    } else if (idx < 98304) {
        int i = idx - 65536; int out = i >> 8, k = i & 255;
        float v = (out < 64) ? Wl2[out * 256 + k] : Wr2[(out - 64) * 256 + k];
        int ks = k >> 5, quad = (k >> 3) & 3, e = k & 7, col = out & 15;
        int g = (out >> 4) * 8 + ks;
        W2s[(g * 64 + quad * 16 + col) * 8 + e] = f2bf(v);
    } else if (idx < 114688) {
        int i = idx - 98304;
        int out = i >> 6, k = i & 63;
        float v = fc1W[i];
        int ks = k >> 5, quad = (k >> 3) & 3, e = k & 7, col = out & 15;
        int g = (out >> 4) * 2 + ks;
        F1s[(g * 64 + quad * 16 + col) * 8 + e] = f2bf(v);
    } else if (idx < 147456) {
        int i = idx - 114688;
        int out = i >> 8, k = i & 255;
        float v = fc2W[i];
        int ks = k >> 5, quad = (k >> 3) & 3, e = k & 7, col = out & 15;
        int g = (out >> 4) * 8 + ks;
        F2s[(g * 64 + quad * 16 + col) * 8 + e] = f2bf(v);
    }
}

// x fp32 -> bf16 (packed pairs)
__global__ void convert_x(const float4* __restrict__ x4, uint2* __restrict__ xbf2, int total4) {
    int idx = blockIdx.x * blockDim.x + threadIdx.x;
    if (idx >= total4) return;
    float4 v = x4[idx];
    uint2 o;
    o.x = f2bf2(v.x, v.y);
    o.y = f2bf2(v.z, v.w);
    xbf2[idx] = o;
}

// ---------------- counting sort of edges by dst ----------------

__global__ void hist_kernel(const int* __restrict__ dst, int* __restrict__ degI, int E) {
    int e = blockIdx.x * blockDim.x + threadIdx.x;
    if (e >= E) return;
    atomicAdd(&degI[dst[e]], 1);
}

__global__ void scan_block(const int* __restrict__ degI, int* __restrict__ offs,
                           int* __restrict__ bsum, int N) {
    __shared__ int s[SCAN_B];
    int tid = threadIdx.x;
    int gid = blockIdx.x * SCAN_B + tid;
    int v = (gid < N) ? degI[gid] : 0;
    s[tid] = v;
    __syncthreads();
    for (int off = 1; off < SCAN_B; off <<= 1) {
        int t = (tid >= off) ? s[tid - off] : 0;
        __syncthreads();
        s[tid] += t;
        __syncthreads();
    }
    if (gid < N) offs[gid] = s[tid] - v;
    if (tid == SCAN_B - 1) bsum[blockIdx.x] = s[tid];
}

__global__ void scan_bsum(int* __restrict__ bsum, int nb) {
    __shared__ int s[128];
    int tid = threadIdx.x;
    int v = (tid < nb) ? bsum[tid] : 0;
    s[tid] = v;
    __syncthreads();
    for (int off = 1; off < 128; off <<= 1) {
        int t = (tid >= off) ? s[tid - off] : 0;
        __syncthreads();
        s[tid] += t;
        __syncthreads();
    }
    if (tid < nb) bsum[tid] = s[tid] - v;
}

__global__ void scan_add(int* __restrict__ offs, const int* __restrict__ bsum, int N) {
    int gid = blockIdx.x * SCAN_B + threadIdx.x;
    if (gid < N) offs[gid] += bsum[blockIdx.x];
}

// ---------------- two-pass bucketed reorder ----------------
// Pass 1: partition edges into NBUCK buckets of 64 dst nodes. Bucket region in
// the pair array == final srcS region ([offs[b*64], offs[(b+1)*64])). Each
// bucket's cursor advances sequentially -> write streams fill lines fully.
// Pair packs (src | d_local<<20) into one uint -> 6.4MB.
__global__ __launch_bounds__(256) void bucket_partition(
        const int* __restrict__ src, const int* __restrict__ dst,
        const int* __restrict__ offs, int* __restrict__ bcur,
        unsigned* __restrict__ pairs, int E) {
    int e = blockIdx.x * blockDim.x + threadIdx.x;
    if (e >= E) return;
    int d = dst[e];
    int b = d >> BSHIFT;
    int pos = offs[d & ~63] + atomicAdd(&bcur[b], 1);
    pairs[pos] = (unsigned)src[e] | ((unsigned)(d & 63) << 20);
}

// Pass 2: one WG per bucket; sequential read of the bucket's pair slice,
// scatter into the bucket's ~4KB srcS window via LDS cursors (no global
// atomics). Window is L2-resident -> written back once.
__global__ __launch_bounds__(256) void bucket_scatter(
        const unsigned* __restrict__ pairs, const int* __restrict__ offs,
        int* __restrict__ srcS, int E) {
    __shared__ int sOffs[64];
    __shared__ int sCur[64];
    const int b = blockIdx.x;
    const int lo = b << BSHIFT;
    const int t = threadIdx.x;
    if (t < 64) {
        int node = lo + t;
        sOffs[t] = (node < N_NODES) ? offs[node] : E;
        sCur[t] = 0;
    }
    __syncthreads();
    const int start = sOffs[0];
    const int endNode = lo + 64;
    const int end = (endNode < N_NODES) ? offs[endNode] : E;
    for (int i = start + t; i < end; i += 256) {
        unsigned p = pairs[i];
        int srcv = (int)(p & 0xFFFFFu);
        int dl = (int)(p >> 20);
        int pos = sOffs[dl] + atomicAdd(&sCur[dl], 1);
        srcS[pos] = srcv;
    }
}

// ---------------- gather: mean of bf16 x rows -> packed bf16 mean ----------------
// one wave per node; lane = uint = 2 features (128 feats total)
__global__ __launch_bounds__(256) void gather_mean_bf(
        const unsigned* __restrict__ xbfu, const int* __restrict__ srcS,
        const int* __restrict__ offs, const int* __restrict__ degI,
        unsigned* __restrict__ meanbf) {
    const int wave = threadIdx.x >> 6, lane = threadIdx.x & 63;
    const int n = blockIdx.x * 4 + wave;
    if (n >= N_NODES) return;
    const int start = offs[n], cnt = degI[n];
    const int* sp = srcS + start;
    float2 a0 = {0.f, 0.f}, a1 = {0.f, 0.f}, a2 = {0.f, 0.f}, a3 = {0.f, 0.f};
    float2 a4 = {0.f, 0.f}, a5 = {0.f, 0.f}, a6 = {0.f, 0.f}, a7 = {0.f, 0.f};
    int j = 0;
    for (; j + 8 <= cnt; j += 8) {
        unsigned v0 = xbfu[sp[j]     * 64 + lane];
        unsigned v1 = xbfu[sp[j + 1] * 64 + lane];
        unsigned v2 = xbfu[sp[j + 2] * 64 + lane];
        unsigned v3 = xbfu[sp[j + 3] * 64 + lane];
        unsigned v4 = xbfu[sp[j + 4] * 64 + lane];
        unsigned v5 = xbfu[sp[j + 5] * 64 + lane];
        unsigned v6 = xbfu[sp[j + 6] * 64 + lane];
        unsigned v7 = xbfu[sp[j + 7] * 64 + lane];
        float2 f0 = bf2f2(v0), f1 = bf2f2(v1), f2 = bf2f2(v2), f3 = bf2f2(v3);
        float2 f4 = bf2f2(v4), f5 = bf2f2(v5), f6 = bf2f2(v6), f7 = bf2f2(v7);
        a0.x += f0.x; a0.y += f0.y;  a1.x += f1.x; a1.y += f1.y;
        a2.x += f2.x; a2.y += f2.y;  a3.x += f3.x; a3.y += f3.y;
        a4.x += f4.x; a4.y += f4.y;  a5.x += f5.x; a5.y += f5.y;
        a6.x += f6.x; a6.y += f6.y;  a7.x += f7.x; a7.y += f7.y;
    }
    for (; j + 2 <= cnt; j += 2) {
        float2 f0 = bf2f2(xbfu[sp[j]     * 64 + lane]);
        float2 f1 = bf2f2(xbfu[sp[j + 1] * 64 + lane]);
        a0.x += f0.x; a0.y += f0.y;
        a1.x += f1.x; a1.y += f1.y;
    }
    if (j < cnt) {
        float2 f0 = bf2f2(xbfu[sp[j] * 64 + lane]);
        a0.x += f0.x; a0.y += f0.y;
    }
    float rd = 1.0f / fmaxf((float)cnt, 1.0f);
    float mx = ((a0.x + a1.x) + (a2.x + a3.x)) + ((a4.x + a5.x) + (a6.x + a7.x));
    float my = ((a0.y + a1.y) + (a2.y + a3.y)) + ((a4.y + a5.y) + (a6.y + a7.y));
    meanbf[n * 64 + lane] = f2bf2(mx * rd, my * rd);
}

// ---------------- layer1 MFMA: [mean|x] -> h -> [z2|r2] ----------------
__global__ __launch_bounds__(256, 4) void layer1_mfma(
        const unsigned* __restrict__ xbfu, const unsigned* __restrict__ meanbf,
        const unsigned short* __restrict__ W1s, const float* __restrict__ bl1,
        const unsigned short* __restrict__ W2s,
        unsigned short* __restrict__ z2bf, float* __restrict__ embOut) {
    __shared__ unsigned short sA[MT][264];
    __shared__ unsigned short sH[MT][264];
    const int tid = threadIdx.x;
    const int node0 = blockIdx.x * MT;

    // staging: 1024 x 16B chunks (mean -> cols 0:128, x -> cols 128:256)
    const uint4* mean4 = (const uint4*)meanbf;
    const uint4* x4    = (const uint4*)xbfu;
#pragma unroll
    for (int it = 0; it < 4; it++) {
        int c = tid + it * 256;
        int row = c >> 5, half = (c >> 4) & 1, ci = c & 15;
        uint4 v = half ? x4[(node0 + row) * 16 + ci]
                       : mean4[(node0 + row) * 16 + ci];
        *(uint4*)&sA[row][half * 128 + ci * 8] = v;
    }
    __syncthreads();

    const int wave = tid >> 6, lane = tid & 63;
    const int col = lane & 15, quad = lane >> 4;

    // ---- phase A: h = relu(A @ W1^T + bl1), N=256, K=256 ----
    floatx4 acc[2][4];
    const floatx4 zero = {0.f, 0.f, 0.f, 0.f};
#pragma unroll
    for (int mt = 0; mt < 2; mt++)
#pragma unroll
        for (int nt = 0; nt < 4; nt++) acc[mt][nt] = zero;

    const short8* w1base = (const short8*)W1s + wave * 2048 + lane;
#pragma unroll
    for (int ks = 0; ks < 8; ks++) {
        short8 a0 = *(const short8*)&sA[col][ks * 32 + quad * 8];
        short8 a1 = *(const short8*)&sA[16 + col][ks * 32 + quad * 8];
#pragma unroll
        for (int nt = 0; nt < 4; nt++) {
            short8 b = w1base[(nt * 8 + ks) * 64];
            acc[0][nt] = MFMA16(a0, b, acc[0][nt]);
            acc[1][nt] = MFMA16(a1, b, acc[1][nt]);
        }
    }

#pragma unroll
    for (int nt = 0; nt < 4; nt++) {
        int out = (wave * 4 + nt) * 16 + col;
        float bias = bl1[out];
#pragma unroll
        for (int mt = 0; mt < 2; mt++)
#pragma unroll
            for (int r = 0; r < 4; r++)
                sH[mt * 16 + quad * 4 + r][out] = f2bf(fmaxf(acc[mt][nt][r] + bias, 0.f));
    }
    __syncthreads();

    // ---- phase B: [z2|r2] = h @ W2^T, N=128, K=256 ----
    floatx4 acc2[2][2];
#pragma unroll
    for (int mt = 0; mt < 2; mt++)
#pragma unroll
        for (int nt = 0; nt < 2; nt++) acc2[mt][nt] = zero;

    const short8* w2base = (const short8*)W2s + wave * 1024 + lane;
#pragma unroll
    for (int ks = 0; ks < 8; ks++) {
        short8 h0 = *(const short8*)&sH[col][ks * 32 + quad * 8];
        short8 h1 = *(const short8*)&sH[16 + col][ks * 32 + quad * 8];
#pragma unroll
        for (int nt = 0; nt < 2; nt++) {
            short8 b = w2base[(nt * 8 + ks) * 64];
            acc2[0][nt] = MFMA16(h0, b, acc2[0][nt]);
            acc2[1][nt] = MFMA16(h1, b, acc2[1][nt]);
        }
    }

#pragma unroll
    for (int nt = 0; nt < 2; nt++) {
        int out = (wave * 2 + nt) * 16 + col;
#pragma unroll
        for (int mt = 0; mt < 2; mt++)
#pragma unroll
            for (int r = 0; r < 4; r++) {
                int node = node0 + mt * 16 + quad * 4 + r;
                float v = acc2[mt][nt][r];
                if (out < 64) z2bf[node * 64 + out] = f2bf(v);
                else          embOut[node * 64 + (out - 64)] = v;
            }
    }
}

// ---------------- gather: emb = agg(z2)/deg + bl2 + r2 ----------------
__global__ __launch_bounds__(256) void gather_emb(
        const unsigned* __restrict__ z2u, const int* __restrict__ srcS,
        const int* __restrict__ offs, const int* __restrict__ degI,
        const float* __restrict__ bl2, float* __restrict__ emb,
        unsigned* __restrict__ embbf) {
    const int wave = threadIdx.x >> 6, lane = threadIdx.x & 63;
    const int n = blockIdx.x * 4 + wave;
    if (n >= N_NODES) return;
    const int start = offs[n], cnt = degI[n];
    const int* sp = srcS + start;
    const int half = lane >> 5, l32 = lane & 31;
    float a0x = 0.f, a0y = 0.f, a1x = 0.f, a1y = 0.f;
    float a2x = 0.f, a2y = 0.f, a3x = 0.f, a3y = 0.f;
    int j = 0;
    for (; j + 8 <= cnt; j += 8) {
        unsigned v0 = z2u[sp[j + half]     * 32 + l32];
        unsigned v1 = z2u[sp[j + 2 + half] * 32 + l32];
        unsigned v2 = z2u[sp[j + 4 + half] * 32 + l32];
        unsigned v3 = z2u[sp[j + 6 + half] * 32 + l32];
        float2 f0 = bf2f2(v0), f1 = bf2f2(v1), f2 = bf2f2(v2), f3 = bf2f2(v3);
        a0x += f0.x; a0y += f0.y;  a1x += f1.x; a1y += f1.y;
        a2x += f2.x; a2y += f2.y;  a3x += f3.x; a3y += f3.y;
    }
    for (; j + 2 <= cnt; j += 2) {
        float2 f0 = bf2f2(z2u[sp[j + half] * 32 + l32]);
        a0x += f0.x; a0y += f0.y;
    }
    if ((cnt & 1) && half == 0) {
        float2 f0 = bf2f2(z2u[sp[cnt - 1] * 32 + l32]);
        a0x += f0.x; a0y += f0.y;
    }
    float ax = (a0x + a1x) + (a2x + a3x);
    float ay = (a0y + a1y) + (a2y + a3y);
    ax += __shfl_down(ax, 32);
    ay += __shfl_down(ay, 32);
    if (half == 0) {
        float rd = 1.0f / fmaxf((float)cnt, 1.0f);
        float2 r2v = *(const float2*)&emb[n * 64 + l32 * 2];
        float ex = ax * rd + bl2[l32 * 2]     + r2v.x;
        float ey = ay * rd + bl2[l32 * 2 + 1] + r2v.y;
        float2 ev = {ex, ey};
        *(float2*)&emb[n * 64 + l32 * 2] = ev;
        embbf[n * 32 + l32] = f2bf2(ex, ey);
    }
}

// ---------------- decoder MFMA: emb -> hid -> recon ----------------
__global__ __launch_bounds__(256, 4) void decoder_mfma(
        const unsigned* __restrict__ embbf,
        const unsigned short* __restrict__ F1s, const float* __restrict__ fc1b,
        const unsigned short* __restrict__ F2s, const float* __restrict__ fc2b,
        float* __restrict__ recon) {
    __shared__ unsigned short sE[MT][72];
    __shared__ unsigned short sH[MT][264];
    const int tid = threadIdx.x;
    const int node0 = blockIdx.x * MT;

    // staging: 256 x 16B chunks, 1 per thread
    {
        const uint4* e4 = (const uint4*)embbf;
        int row = tid >> 3, ci = tid & 7;
        *(uint4*)&sE[row][ci * 8] = e4[(node0 + row) * 8 + ci];
    }
    __syncthreads();

    const int wave = tid >> 6, lane = tid & 63;
    const int col = lane & 15, quad = lane >> 4;

    // ---- phase A: hid = relu(emb @ fc1^T + fc1b), N=256, K=64 ----
    floatx4 acc[2][4];
    const floatx4 zero = {0.f, 0.f, 0.f, 0.f};
#pragma unroll
    for (int mt = 0; mt < 2; mt++)
#pragma unroll
        for (int nt = 0; nt < 4; nt++) acc[mt][nt] = zero;

    const short8* f1base = (const short8*)F1s + wave * 512 + lane;
#pragma unroll
    for (int ks = 0; ks < 2; ks++) {
        short8 a0 = *(const short8*)&sE[col][ks * 32 + quad * 8];
        short8 a1 = *(const short8*)&sE[16 + col][ks * 32 + quad * 8];
#pragma unroll
        for (int nt = 0; nt < 4; nt++) {
            short8 b = f1base[(nt * 2 + ks) * 64];
            acc[0][nt] = MFMA16(a0, b, acc[0][nt]);
            acc[1][nt] = MFMA16(a1, b, acc[1][nt]);
        }
    }

#pragma unroll
    for (int nt = 0; nt < 4; nt++) {
        int out = (wave * 4 + nt) * 16 + col;
        float bias = fc1b[out];
#pragma unroll
        for (int mt = 0; mt < 2; mt++)
#pragma unroll
            for (int r = 0; r < 4; r++)
                sH[mt * 16 + quad * 4 + r][out] = f2bf(fmaxf(acc[mt][nt][r] + bias, 0.f));
    }
    __syncthreads();

    // ---- phase B: recon = hid @ fc2^T + fc2b, N=128, K=256 ----
    floatx4 acc2[2][2];
#pragma unroll
    for (int mt = 0; mt < 2; mt++)
#pragma unroll
        for (int nt = 0; nt < 2; nt++) acc2[mt][nt] = zero;

    const short8* f2base = (const short8*)F2s + wave * 1024 + lane;
#pragma unroll
    for (int ks = 0; ks < 8; ks++) {
        short8 h0 = *(const short8*)&sH[col][ks * 32 + quad * 8];
        short8 h1 = *(const short8*)&sH[16 + col][ks * 32 + quad * 8];
#pragma unroll
        for (int nt = 0; nt < 2; nt++) {
            short8 b = f2base[(nt * 8 + ks) * 64];
            acc2[0][nt] = MFMA16(h0, b, acc2[0][nt]);
            acc2[1][nt] = MFMA16(h1, b, acc2[1][nt]);
        }
    }

#pragma unroll
    for (int nt = 0; nt < 2; nt++) {
        int out = (wave * 2 + nt) * 16 + col;
        float bias = fc2b[out];
#pragma unroll
        for (int mt = 0; mt < 2; mt++)
#pragma unroll
            for (int r = 0; r < 4; r++) {
                int node = node0 + mt * 16 + quad * 4 + r;
                recon[node * 128 + out] = acc2[mt][nt][r] + bias;
            }
    }
}

extern "C" void kernel_launch(void* const* d_in, const int* in_sizes, int n_in,
                              void* d_out, int out_size, void* d_ws, size_t ws_size,
                              hipStream_t stream) {
    const float* x    = (const float*)d_in[0];
    const int*   ei   = (const int*)d_in[1];
    const int E = in_sizes[1] / 2;
    const int* src = ei;
    const int* dst = ei + E;
    const float* Wl1  = (const float*)d_in[2];
    const float* bl1  = (const float*)d_in[3];
    const float* Wr1  = (const float*)d_in[4];
    const float* Wl2  = (const float*)d_in[5];
    const float* bl2  = (const float*)d_in[6];
    const float* Wr2  = (const float*)d_in[7];
    const float* fc1W = (const float*)d_in[8];
    const float* fc1b = (const float*)d_in[9];
    const float* fc2W = (const float*)d_in[10];
    const float* fc2b = (const float*)d_in[11];

    float* out   = (float*)d_out;
    float* emb   = out;                           // N*64
    float* recon = out + (size_t)N_NODES * D_E;   // N*128

    // workspace layout (512-aligned offsets)
    char* ws = (char*)d_ws;
    unsigned short* xbf    = (unsigned short*)(ws);             // 25,600,000 B
    unsigned*       meanbf = (unsigned*)(ws + 25600000);        // 25,600,000 B
    unsigned short* z2bf   = (unsigned short*)(ws + 51200000);  // 12,800,000 B
    unsigned*       embbf  = (unsigned*)(ws + 64000000);        // 12,800,000 B
    int* degI   = (int*)(ws + 76800000);                        //    400,000 B
    int* offs   = (int*)(ws + 77200384);                        //    400,000 B
    int* cursor = (int*)(ws + 77600768);                        //    400,000 B
    int* bsum   = (int*)(ws + 78001152);                        //        512 B
    int* srcS   = (int*)(ws + 78001664);                        //  6,400,000 B
    unsigned short* W1s = (unsigned short*)(ws + 84401664);     //    131,072 B
    unsigned short* W2s = (unsigned short*)(ws + 84532736);     //     65,536 B
    unsigned short* F1s = (unsigned short*)(ws + 84598272);     //     32,768 B
    unsigned short* F2s = (unsigned short*)(ws + 84631040);     //     65,536 B
    // end 84,696,576 B
    // pairs buffer (6.4MB) reuses the meanbf region: its lifetime ends before
    // gather_mean_bf writes meanbf.
    unsigned* pairs = (unsigned*)(ws + 25600000);

    hipMemsetAsync(degI,   0, (size_t)N_NODES * sizeof(int), stream);
    hipMemsetAsync(cursor, 0, (size_t)NBUCK * sizeof(int), stream);

    convert_weights<<<(147456 + 255) / 256, 256, 0, stream>>>(
        Wl1, Wr1, Wl2, Wr2, fc1W, fc2W, W1s, W2s, F1s, F2s);
    convert_x<<<(N_NODES * 32 + 255) / 256, 256, 0, stream>>>(
        (const float4*)x, (uint2*)xbf, N_NODES * 32);

    // counting sort of edges by dst (two-pass bucketed)
    hist_kernel<<<(E + 255) / 256, 256, 0, stream>>>(dst, degI, E);
    const int nScanBlocks = (N_NODES + SCAN_B - 1) / SCAN_B;  // 98
    scan_block<<<nScanBlocks, SCAN_B, 0, stream>>>(degI, offs, bsum, N_NODES);
    scan_bsum<<<1, 128, 0, stream>>>(bsum, nScanBlocks);
    scan_add<<<nScanBlocks, SCAN_B, 0, stream>>>(offs, bsum, N_NODES);
    bucket_partition<<<(E + 255) / 256, 256, 0, stream>>>(src, dst, offs, cursor, pairs, E);
    bucket_scatter<<<NBUCK, 256, 0, stream>>>(pairs, offs, srcS, E);

    // layer 1
    gather_mean_bf<<<(N_NODES + 3) / 4, 256, 0, stream>>>(
        (const unsigned*)xbf, srcS, offs, degI, meanbf);
    layer1_mfma<<<N_NODES / MT, 256, 0, stream>>>(
        (const unsigned*)xbf, meanbf, W1s, bl1, W2s, z2bf, emb);

    // layer 2 aggregation + emb finalize
    gather_emb<<<(N_NODES + 3) / 4, 256, 0, stream>>>(
        (const unsigned*)z2bf, srcS, offs, degI, bl2, emb, embbf);

    // decoder
    decoder_mfma<<<N_NODES / MT, 256, 0, stream>>>(
        embbf, F1s, fc1b, F2s, fc2b, recon);
}

// Round 4
// 471.147 us; speedup vs baseline: 1.3453x; 1.3453x over previous
//
#include <hip/hip_runtime.h>
#include <hip/hip_bf16.h>

#define N_NODES 100000
#define D_IN 128
#define D_H 256
#define D_E 64
#define MT 32        // nodes per GEMM block
#define SCAN_B 1024  // scan block size
#define BSHIFT 9                                   // 512 nodes per bucket
#define NBUCK ((N_NODES + 511) >> BSHIFT)          // 196
#define CHUNK 16384                                // edges per pass-1 block

typedef __attribute__((ext_vector_type(8))) short short8;
typedef __attribute__((ext_vector_type(4))) float floatx4;

__device__ inline unsigned short f2bf(float f) {
    union { float f; unsigned u; } v; v.f = f;
    unsigned r = v.u + 0x7FFF + ((v.u >> 16) & 1);
    return (unsigned short)(r >> 16);
}
__device__ inline unsigned f2bf2(float a, float b) {
    return (unsigned)f2bf(a) | ((unsigned)f2bf(b) << 16);
}
__device__ inline float2 bf2f2(unsigned v) {
    union { unsigned u; float f; } lo, hi;
    lo.u = v << 16;
    hi.u = v & 0xffff0000u;
    return make_float2(lo.f, hi.f);  // .x = lower-address bf16
}

#define MFMA16(a, b, c) __builtin_amdgcn_mfma_f32_16x16x32_bf16((a), (b), (c), 0, 0, 0)

// ---------------- weight pre-pack to bf16, SWIZZLED to MFMA fragment order ----
__global__ void convert_weights(const float* __restrict__ Wl1, const float* __restrict__ Wr1,
                                const float* __restrict__ Wl2, const float* __restrict__ Wr2,
                                const float* __restrict__ fc1W, const float* __restrict__ fc2W,
                                unsigned short* __restrict__ W1s, unsigned short* __restrict__ W2s,
                                unsigned short* __restrict__ F1s, unsigned short* __restrict__ F2s) {
    int idx = blockIdx.x * blockDim.x + threadIdx.x;
    if (idx < 65536) {
        int out = idx >> 8, k = idx & 255;
        float v = (k < 128) ? Wl1[out * 128 + k] : Wr1[out * 128 + (k - 128)];
        int ks = k >> 5, quad = (k >> 3) & 3, e = k & 7, col = out & 15;
        int g = (out >> 4) * 8 + ks;
        W1s[(g * 64 + quad * 16 + col) * 8 + e] = f2bf(v);
    } else if (idx < 98304) {
        int i = idx - 65536; int out = i >> 8, k = i & 255;
        float v = (out < 64) ? Wl2[out * 256 + k] : Wr2[(out - 64) * 256 + k];
        int ks = k >> 5, quad = (k >> 3) & 3, e = k & 7, col = out & 15;
        int g = (out >> 4) * 8 + ks;
        W2s[(g * 64 + quad * 16 + col) * 8 + e] = f2bf(v);
    } else if (idx < 114688) {
        int i = idx - 98304;
        int out = i >> 6, k = i & 63;
        float v = fc1W[i];
        int ks = k >> 5, quad = (k >> 3) & 3, e = k & 7, col = out & 15;
        int g = (out >> 4) * 2 + ks;
        F1s[(g * 64 + quad * 16 + col) * 8 + e] = f2bf(v);
    } else if (idx < 147456) {
        int i = idx - 114688;
        int out = i >> 8, k = i & 255;
        float v = fc2W[i];
        int ks = k >> 5, quad = (k >> 3) & 3, e = k & 7, col = out & 15;
        int g = (out >> 4) * 8 + ks;
        F2s[(g * 64 + quad * 16 + col) * 8 + e] = f2bf(v);
    }
}

// x fp32 -> bf16 (packed pairs)
__global__ void convert_x(const float4* __restrict__ x4, uint2* __restrict__ xbf2, int total4) {
    int idx = blockIdx.x * blockDim.x + threadIdx.x;
    if (idx >= total4) return;
    float4 v = x4[idx];
    uint2 o;
    o.x = f2bf2(v.x, v.y);
    o.y = f2bf2(v.z, v.w);
    xbf2[idx] = o;
}

// ---------------- counting sort of edges by dst ----------------

__global__ void hist_kernel(const int* __restrict__ dst, int* __restrict__ degI, int E) {
    int e = blockIdx.x * blockDim.x + threadIdx.x;
    if (e >= E) return;
    atomicAdd(&degI[dst[e]], 1);
}

__global__ void scan_block(const int* __restrict__ degI, int* __restrict__ offs,
                           int* __restrict__ bsum, int N) {
    __shared__ int s[SCAN_B];
    int tid = threadIdx.x;
    int gid = blockIdx.x * SCAN_B + tid;
    int v = (gid < N) ? degI[gid] : 0;
    s[tid] = v;
    __syncthreads();
    for (int off = 1; off < SCAN_B; off <<= 1) {
        int t = (tid >= off) ? s[tid - off] : 0;
        __syncthreads();
        s[tid] += t;
        __syncthreads();
    }
    if (gid < N) offs[gid] = s[tid] - v;
    if (tid == SCAN_B - 1) bsum[blockIdx.x] = s[tid];
}

__global__ void scan_bsum(int* __restrict__ bsum, int nb) {
    __shared__ int s[128];
    int tid = threadIdx.x;
    int v = (tid < nb) ? bsum[tid] : 0;
    s[tid] = v;
    __syncthreads();
    for (int off = 1; off < 128; off <<= 1) {
        int t = (tid >= off) ? s[tid - off] : 0;
        __syncthreads();
        s[tid] += t;
        __syncthreads();
    }
    if (tid < nb) bsum[tid] = s[tid] - v;
}

__global__ void scan_add(int* __restrict__ offs, const int* __restrict__ bsum, int N) {
    int gid = blockIdx.x * SCAN_B + threadIdx.x;
    if (gid < N) offs[gid] += bsum[blockIdx.x];
}

// ---------------- two-pass radix partition (per-block reservation) ----------
// Pass 1: per-block LDS histogram over 196 buckets (512 nodes each), ONE
// line-padded global atomicAdd per (block,bucket) to reserve space, then
// re-walk chunk (dst L2-hot) scattering packed (src | dlocal<<20) with LDS
// cursors. Streams are sequential -> lines fill fully; atomic contention is
// ~98 ops per padded line.
__global__ __launch_bounds__(256) void radix_count_reserve(
        const int* __restrict__ src, const int* __restrict__ dst,
        const int* __restrict__ offs, int* __restrict__ gcur,
        unsigned* __restrict__ pairs, int E) {
    __shared__ int hist[256];
    __shared__ int sBase[256];
    __shared__ int sCur[256];
    const int t = threadIdx.x;
    hist[t] = 0;
    sCur[t] = 0;
    __syncthreads();
    const int e0 = blockIdx.x * CHUNK;
    const int e1 = min(e0 + CHUNK, E);
    for (int e = e0 + t; e < e1; e += 256)
        atomicAdd(&hist[dst[e] >> BSHIFT], 1);
    __syncthreads();
    if (t < NBUCK && hist[t] > 0)
        sBase[t] = offs[t << BSHIFT] + atomicAdd(&gcur[t * 16], hist[t]);
    __syncthreads();
    for (int e = e0 + t; e < e1; e += 256) {
        int d = dst[e];
        int b = d >> BSHIFT;
        int pos = sBase[b] + atomicAdd(&sCur[b], 1);
        pairs[pos] = (unsigned)src[e] | ((unsigned)(d & 511) << 20);
    }
}

// Pass 2: one WG per bucket; sequential read of its ~32KB pair slice, scatter
// into its ~32KB srcS window via LDS cursors (no global atomics; L2-resident).
__global__ __launch_bounds__(256) void radix_scatter(
        const unsigned* __restrict__ pairs, const int* __restrict__ offs,
        int* __restrict__ srcS, int E) {
    __shared__ int sOffs[512];
    __shared__ int sCur[512];
    const int b = blockIdx.x;
    const int lo = b << BSHIFT;
    const int t = threadIdx.x;
    for (int i = t; i < 512; i += 256) {
        int node = lo + i;
        sOffs[i] = (node < N_NODES) ? offs[node] : E;
        sCur[i] = 0;
    }
    __syncthreads();
    const int start = sOffs[0];
    const int endNode = lo + 512;
    const int end = (endNode < N_NODES) ? offs[endNode] : E;
    for (int i = start + t; i < end; i += 256) {
        unsigned p = pairs[i];
        int dl = (int)(p >> 20);
        int pos = sOffs[dl] + atomicAdd(&sCur[dl], 1);
        srcS[pos] = (int)(p & 0xFFFFFu);
    }
}

// ---------------- gather: mean of bf16 x rows -> packed bf16 mean ----------------
// one wave per node; lane = uint = 2 features (128 feats total)
__global__ __launch_bounds__(256) void gather_mean_bf(
        const unsigned* __restrict__ xbfu, const int* __restrict__ srcS,
        const int* __restrict__ offs, const int* __restrict__ degI,
        unsigned* __restrict__ meanbf) {
    const int wave = threadIdx.x >> 6, lane = threadIdx.x & 63;
    const int n = blockIdx.x * 4 + wave;
    if (n >= N_NODES) return;
    const int start = offs[n], cnt = degI[n];
    const int* sp = srcS + start;
    float2 a0 = {0.f, 0.f}, a1 = {0.f, 0.f}, a2 = {0.f, 0.f}, a3 = {0.f, 0.f};
    float2 a4 = {0.f, 0.f}, a5 = {0.f, 0.f}, a6 = {0.f, 0.f}, a7 = {0.f, 0.f};
    int j = 0;
    for (; j + 8 <= cnt; j += 8) {
        unsigned v0 = xbfu[sp[j]     * 64 + lane];
        unsigned v1 = xbfu[sp[j + 1] * 64 + lane];
        unsigned v2 = xbfu[sp[j + 2] * 64 + lane];
        unsigned v3 = xbfu[sp[j + 3] * 64 + lane];
        unsigned v4 = xbfu[sp[j + 4] * 64 + lane];
        unsigned v5 = xbfu[sp[j + 5] * 64 + lane];
        unsigned v6 = xbfu[sp[j + 6] * 64 + lane];
        unsigned v7 = xbfu[sp[j + 7] * 64 + lane];
        float2 f0 = bf2f2(v0), f1 = bf2f2(v1), f2 = bf2f2(v2), f3 = bf2f2(v3);
        float2 f4 = bf2f2(v4), f5 = bf2f2(v5), f6 = bf2f2(v6), f7 = bf2f2(v7);
        a0.x += f0.x; a0.y += f0.y;  a1.x += f1.x; a1.y += f1.y;
        a2.x += f2.x; a2.y += f2.y;  a3.x += f3.x; a3.y += f3.y;
        a4.x += f4.x; a4.y += f4.y;  a5.x += f5.x; a5.y += f5.y;
        a6.x += f6.x; a6.y += f6.y;  a7.x += f7.x; a7.y += f7.y;
    }
    for (; j + 2 <= cnt; j += 2) {
        float2 f0 = bf2f2(xbfu[sp[j]     * 64 + lane]);
        float2 f1 = bf2f2(xbfu[sp[j + 1] * 64 + lane]);
        a0.x += f0.x; a0.y += f0.y;
        a1.x += f1.x; a1.y += f1.y;
    }
    if (j < cnt) {
        float2 f0 = bf2f2(xbfu[sp[j] * 64 + lane]);
        a0.x += f0.x; a0.y += f0.y;
    }
    float rd = 1.0f / fmaxf((float)cnt, 1.0f);
    float mx = ((a0.x + a1.x) + (a2.x + a3.x)) + ((a4.x + a5.x) + (a6.x + a7.x));
    float my = ((a0.y + a1.y) + (a2.y + a3.y)) + ((a4.y + a5.y) + (a6.y + a7.y));
    meanbf[n * 64 + lane] = f2bf2(mx * rd, my * rd);
}

// ---------------- layer1 MFMA: [mean|x] -> h -> [z2|r2] ----------------
__global__ __launch_bounds__(256, 4) void layer1_mfma(
        const unsigned* __restrict__ xbfu, const unsigned* __restrict__ meanbf,
        const unsigned short* __restrict__ W1s, const float* __restrict__ bl1,
        const unsigned short* __restrict__ W2s,
        unsigned short* __restrict__ z2bf, float* __restrict__ embOut) {
    __shared__ unsigned short sA[MT][264];
    __shared__ unsigned short sH[MT][264];
    const int tid = threadIdx.x;
    const int node0 = blockIdx.x * MT;

    // staging: 1024 x 16B chunks (mean -> cols 0:128, x -> cols 128:256)
    const uint4* mean4 = (const uint4*)meanbf;
    const uint4* x4    = (const uint4*)xbfu;
#pragma unroll
    for (int it = 0; it < 4; it++) {
        int c = tid + it * 256;
        int row = c >> 5, half = (c >> 4) & 1, ci = c & 15;
        uint4 v = half ? x4[(node0 + row) * 16 + ci]
                       : mean4[(node0 + row) * 16 + ci];
        *(uint4*)&sA[row][half * 128 + ci * 8] = v;
    }
    __syncthreads();

    const int wave = tid >> 6, lane = tid & 63;
    const int col = lane & 15, quad = lane >> 4;

    // ---- phase A: h = relu(A @ W1^T + bl1), N=256, K=256 ----
    floatx4 acc[2][4];
    const floatx4 zero = {0.f, 0.f, 0.f, 0.f};
#pragma unroll
    for (int mt = 0; mt < 2; mt++)
#pragma unroll
        for (int nt = 0; nt < 4; nt++) acc[mt][nt] = zero;

    const short8* w1base = (const short8*)W1s + wave * 2048 + lane;
#pragma unroll
    for (int ks = 0; ks < 8; ks++) {
        short8 a0 = *(const short8*)&sA[col][ks * 32 + quad * 8];
        short8 a1 = *(const short8*)&sA[16 + col][ks * 32 + quad * 8];
#pragma unroll
        for (int nt = 0; nt < 4; nt++) {
            short8 b = w1base[(nt * 8 + ks) * 64];
            acc[0][nt] = MFMA16(a0, b, acc[0][nt]);
            acc[1][nt] = MFMA16(a1, b, acc[1][nt]);
        }
    }

#pragma unroll
    for (int nt = 0; nt < 4; nt++) {
        int out = (wave * 4 + nt) * 16 + col;
        float bias = bl1[out];
#pragma unroll
        for (int mt = 0; mt < 2; mt++)
#pragma unroll
            for (int r = 0; r < 4; r++)
                sH[mt * 16 + quad * 4 + r][out] = f2bf(fmaxf(acc[mt][nt][r] + bias, 0.f));
    }
    __syncthreads();

    // ---- phase B: [z2|r2] = h @ W2^T, N=128, K=256 ----
    floatx4 acc2[2][2];
#pragma unroll
    for (int mt = 0; mt < 2; mt++)
#pragma unroll
        for (int nt = 0; nt < 2; nt++) acc2[mt][nt] = zero;

    const short8* w2base = (const short8*)W2s + wave * 1024 + lane;
#pragma unroll
    for (int ks = 0; ks < 8; ks++) {
        short8 h0 = *(const short8*)&sH[col][ks * 32 + quad * 8];
        short8 h1 = *(const short8*)&sH[16 + col][ks * 32 + quad * 8];
#pragma unroll
        for (int nt = 0; nt < 2; nt++) {
            short8 b = w2base[(nt * 8 + ks) * 64];
            acc2[0][nt] = MFMA16(h0, b, acc2[0][nt]);
            acc2[1][nt] = MFMA16(h1, b, acc2[1][nt]);
        }
    }

#pragma unroll
    for (int nt = 0; nt < 2; nt++) {
        int out = (wave * 2 + nt) * 16 + col;
#pragma unroll
        for (int mt = 0; mt < 2; mt++)
#pragma unroll
            for (int r = 0; r < 4; r++) {
                int node = node0 + mt * 16 + quad * 4 + r;
                float v = acc2[mt][nt][r];
                if (out < 64) z2bf[node * 64 + out] = f2bf(v);
                else          embOut[node * 64 + (out - 64)] = v;
            }
    }
}

// ---------------- gather: emb = agg(z2)/deg + bl2 + r2 ----------------
__global__ __launch_bounds__(256) void gather_emb(
        const unsigned* __restrict__ z2u, const int* __restrict__ srcS,
        const int* __restrict__ offs, const int* __restrict__ degI,
        const float* __restrict__ bl2, float* __restrict__ emb,
        unsigned* __restrict__ embbf) {
    const int wave = threadIdx.x >> 6, lane = threadIdx.x & 63;
    const int n = blockIdx.x * 4 + wave;
    if (n >= N_NODES) return;
    const int start = offs[n], cnt = degI[n];
    const int* sp = srcS + start;
    const int half = lane >> 5, l32 = lane & 31;
    float a0x = 0.f, a0y = 0.f, a1x = 0.f, a1y = 0.f;
    float a2x = 0.f, a2y = 0.f, a3x = 0.f, a3y = 0.f;
    int j = 0;
    for (; j + 8 <= cnt; j += 8) {
        unsigned v0 = z2u[sp[j + half]     * 32 + l32];
        unsigned v1 = z2u[sp[j + 2 + half] * 32 + l32];
        unsigned v2 = z2u[sp[j + 4 + half] * 32 + l32];
        unsigned v3 = z2u[sp[j + 6 + half] * 32 + l32];
        float2 f0 = bf2f2(v0), f1 = bf2f2(v1), f2 = bf2f2(v2), f3 = bf2f2(v3);
        a0x += f0.x; a0y += f0.y;  a1x += f1.x; a1y += f1.y;
        a2x += f2.x; a2y += f2.y;  a3x += f3.x; a3y += f3.y;
    }
    for (; j + 2 <= cnt; j += 2) {
        float2 f0 = bf2f2(z2u[sp[j + half] * 32 + l32]);
        a0x += f0.x; a0y += f0.y;
    }
    if ((cnt & 1) && half == 0) {
        float2 f0 = bf2f2(z2u[sp[cnt - 1] * 32 + l32]);
        a0x += f0.x; a0y += f0.y;
    }
    float ax = (a0x + a1x) + (a2x + a3x);
    float ay = (a0y + a1y) + (a2y + a3y);
    ax += __shfl_down(ax, 32);
    ay += __shfl_down(ay, 32);
    if (half == 0) {
        float rd = 1.0f / fmaxf((float)cnt, 1.0f);
        float2 r2v = *(const float2*)&emb[n * 64 + l32 * 2];
        float ex = ax * rd + bl2[l32 * 2]     + r2v.x;
        float ey = ay * rd + bl2[l32 * 2 + 1] + r2v.y;
        float2 ev = {ex, ey};
        *(float2*)&emb[n * 64 + l32 * 2] = ev;
        embbf[n * 32 + l32] = f2bf2(ex, ey);
    }
}

// ---------------- decoder MFMA: emb -> hid -> recon ----------------
__global__ __launch_bounds__(256, 4) void decoder_mfma(
        const unsigned* __restrict__ embbf,
        const unsigned short* __restrict__ F1s, const float* __restrict__ fc1b,
        const unsigned short* __restrict__ F2s, const float* __restrict__ fc2b,
        float* __restrict__ recon) {
    __shared__ unsigned short sE[MT][72];
    __shared__ unsigned short sH[MT][264];
    const int tid = threadIdx.x;
    const int node0 = blockIdx.x * MT;

    // staging: 256 x 16B chunks, 1 per thread
    {
        const uint4* e4 = (const uint4*)embbf;
        int row = tid >> 3, ci = tid & 7;
        *(uint4*)&sE[row][ci * 8] = e4[(node0 + row) * 8 + ci];
    }
    __syncthreads();

    const int wave = tid >> 6, lane = tid & 63;
    const int col = lane & 15, quad = lane >> 4;

    // ---- phase A: hid = relu(emb @ fc1^T + fc1b), N=256, K=64 ----
    floatx4 acc[2][4];
    const floatx4 zero = {0.f, 0.f, 0.f, 0.f};
#pragma unroll
    for (int mt = 0; mt < 2; mt++)
#pragma unroll
        for (int nt = 0; nt < 4; nt++) acc[mt][nt] = zero;

    const short8* f1base = (const short8*)F1s + wave * 512 + lane;
#pragma unroll
    for (int ks = 0; ks < 2; ks++) {
        short8 a0 = *(const short8*)&sE[col][ks * 32 + quad * 8];
        short8 a1 = *(const short8*)&sE[16 + col][ks * 32 + quad * 8];
#pragma unroll
        for (int nt = 0; nt < 4; nt++) {
            short8 b = f1base[(nt * 2 + ks) * 64];
            acc[0][nt] = MFMA16(a0, b, acc[0][nt]);
            acc[1][nt] = MFMA16(a1, b, acc[1][nt]);
        }
    }

#pragma unroll
    for (int nt = 0; nt < 4; nt++) {
        int out = (wave * 4 + nt) * 16 + col;
        float bias = fc1b[out];
#pragma unroll
        for (int mt = 0; mt < 2; mt++)
#pragma unroll
            for (int r = 0; r < 4; r++)
                sH[mt * 16 + quad * 4 + r][out] = f2bf(fmaxf(acc[mt][nt][r] + bias, 0.f));
    }
    __syncthreads();

    // ---- phase B: recon = hid @ fc2^T + fc2b, N=128, K=256 ----
    floatx4 acc2[2][2];
#pragma unroll
    for (int mt = 0; mt < 2; mt++)
#pragma unroll
        for (int nt = 0; nt < 2; nt++) acc2[mt][nt] = zero;

    const short8* f2base = (const short8*)F2s + wave * 1024 + lane;
#pragma unroll
    for (int ks = 0; ks < 8; ks++) {
        short8 h0 = *(const short8*)&sH[col][ks * 32 + quad * 8];
        short8 h1 = *(const short8*)&sH[16 + col][ks * 32 + quad * 8];
#pragma unroll
        for (int nt = 0; nt < 2; nt++) {
            short8 b = f2base[(nt * 8 + ks) * 64];
            acc2[0][nt] = MFMA16(h0, b, acc2[0][nt]);
            acc2[1][nt] = MFMA16(h1, b, acc2[1][nt]);
        }
    }

#pragma unroll
    for (int nt = 0; nt < 2; nt++) {
        int out = (wave * 2 + nt) * 16 + col;
        float bias = fc2b[out];
#pragma unroll
        for (int mt = 0; mt < 2; mt++)
#pragma unroll
            for (int r = 0; r < 4; r++) {
                int node = node0 + mt * 16 + quad * 4 + r;
                recon[node * 128 + out] = acc2[mt][nt][r] + bias;
            }
    }
}

extern "C" void kernel_launch(void* const* d_in, const int* in_sizes, int n_in,
                              void* d_out, int out_size, void* d_ws, size_t ws_size,
                              hipStream_t stream) {
    const float* x    = (const float*)d_in[0];
    const int*   ei   = (const int*)d_in[1];
    const int E = in_sizes[1] / 2;
    const int* src = ei;
    const int* dst = ei + E;
    const float* Wl1  = (const float*)d_in[2];
    const float* bl1  = (const float*)d_in[3];
    const float* Wr1  = (const float*)d_in[4];
    const float* Wl2  = (const float*)d_in[5];
    const float* bl2  = (const float*)d_in[6];
    const float* Wr2  = (const float*)d_in[7];
    const float* fc1W = (const float*)d_in[8];
    const float* fc1b = (const float*)d_in[9];
    const float* fc2W = (const float*)d_in[10];
    const float* fc2b = (const float*)d_in[11];

    float* out   = (float*)d_out;
    float* emb   = out;                           // N*64
    float* recon = out + (size_t)N_NODES * D_E;   // N*128

    // workspace layout (512-aligned offsets)
    char* ws = (char*)d_ws;
    unsigned short* xbf    = (unsigned short*)(ws);             // 25,600,000 B
    unsigned*       meanbf = (unsigned*)(ws + 25600000);        // 25,600,000 B
    unsigned short* z2bf   = (unsigned short*)(ws + 51200000);  // 12,800,000 B
    unsigned*       embbf  = (unsigned*)(ws + 64000000);        // 12,800,000 B
    int* degI   = (int*)(ws + 76800000);                        //    400,000 B
    int* offs   = (int*)(ws + 77200384);                        //    400,000 B
    int* gcur   = (int*)(ws + 77600768);                        // 196*64 B padded counters
    int* bsum   = (int*)(ws + 78001152);                        //        512 B
    int* srcS   = (int*)(ws + 78001664);                        //  6,400,000 B
    unsigned short* W1s = (unsigned short*)(ws + 84401664);     //    131,072 B
    unsigned short* W2s = (unsigned short*)(ws + 84532736);     //     65,536 B
    unsigned short* F1s = (unsigned short*)(ws + 84598272);     //     32,768 B
    unsigned short* F2s = (unsigned short*)(ws + 84631040);     //     65,536 B
    // end 84,696,576 B
    // pairs buffer (6.4MB) reuses the meanbf region: its lifetime ends before
    // gather_mean_bf writes meanbf.
    unsigned* pairs = (unsigned*)(ws + 25600000);

    hipMemsetAsync(degI, 0, (size_t)N_NODES * sizeof(int), stream);
    hipMemsetAsync(gcur, 0, (size_t)NBUCK * 16 * sizeof(int), stream);

    convert_weights<<<(147456 + 255) / 256, 256, 0, stream>>>(
        Wl1, Wr1, Wl2, Wr2, fc1W, fc2W, W1s, W2s, F1s, F2s);
    convert_x<<<(N_NODES * 32 + 255) / 256, 256, 0, stream>>>(
        (const float4*)x, (uint2*)xbf, N_NODES * 32);

    // counting sort of edges by dst (radix two-pass)
    hist_kernel<<<(E + 255) / 256, 256, 0, stream>>>(dst, degI, E);
    const int nScanBlocks = (N_NODES + SCAN_B - 1) / SCAN_B;  // 98
    scan_block<<<nScanBlocks, SCAN_B, 0, stream>>>(degI, offs, bsum, N_NODES);
    scan_bsum<<<1, 128, 0, stream>>>(bsum, nScanBlocks);
    scan_add<<<nScanBlocks, SCAN_B, 0, stream>>>(offs, bsum, N_NODES);
    radix_count_reserve<<<(E + CHUNK - 1) / CHUNK, 256, 0, stream>>>(
        src, dst, offs, gcur, pairs, E);
    radix_scatter<<<NBUCK, 256, 0, stream>>>(pairs, offs, srcS, E);

    // layer 1
    gather_mean_bf<<<(N_NODES + 3) / 4, 256, 0, stream>>>(
        (const unsigned*)xbf, srcS, offs, degI, meanbf);
    layer1_mfma<<<N_NODES / MT, 256, 0, stream>>>(
        (const unsigned*)xbf, meanbf, W1s, bl1, W2s, z2bf, emb);

    // layer 2 aggregation + emb finalize
    gather_emb<<<(N_NODES + 3) / 4, 256, 0, stream>>>(
        (const unsigned*)z2bf, srcS, offs, degI, bl2, emb, embbf);

    // decoder
    decoder_mfma<<<N_NODES / MT, 256, 0, stream>>>(
        embbf, F1s, fc1b, F2s, fc2b, recon);
}

// Round 6
// 409.463 us; speedup vs baseline: 1.5479x; 1.1506x over previous
//
#include <hip/hip_runtime.h>
#include <hip/hip_bf16.h>

#define N_NODES 100000
#define D_IN 128
#define D_H 256
#define D_E 64
#define MT 32        // nodes per GEMM block
#define SCAN_B 1024  // scan block size
#define BSHIFT 9                                   // 512 nodes per bucket
#define NBUCK ((N_NODES + 511) >> BSHIFT)          // 196
#define CHUNK 8192                                 // edges per pass-1 block
#define RCR_T 1024                                 // pass-1 threads
#define RCR_ILP (CHUNK / RCR_T)                    // 8 edges per thread

typedef __attribute__((ext_vector_type(8))) short short8;
typedef __attribute__((ext_vector_type(4))) float floatx4;

__device__ inline unsigned short f2bf(float f) {
    union { float f; unsigned u; } v; v.f = f;
    unsigned r = v.u + 0x7FFF + ((v.u >> 16) & 1);
    return (unsigned short)(r >> 16);
}
__device__ inline unsigned f2bf2(float a, float b) {
    return (unsigned)f2bf(a) | ((unsigned)f2bf(b) << 16);
}
__device__ inline float2 bf2f2(unsigned v) {
    union { unsigned u; float f; } lo, hi;
    lo.u = v << 16;
    hi.u = v & 0xffff0000u;
    return make_float2(lo.f, hi.f);  // .x = lower-address bf16
}

#define MFMA16(a, b, c) __builtin_amdgcn_mfma_f32_16x16x32_bf16((a), (b), (c), 0, 0, 0)

// ---------------- weight pre-pack to bf16, SWIZZLED to MFMA fragment order ----
__global__ void convert_weights(const float* __restrict__ Wl1, const float* __restrict__ Wr1,
                                const float* __restrict__ Wl2, const float* __restrict__ Wr2,
                                const float* __restrict__ fc1W, const float* __restrict__ fc2W,
                                unsigned short* __restrict__ W1s, unsigned short* __restrict__ W2s,
                                unsigned short* __restrict__ F1s, unsigned short* __restrict__ F2s) {
    int idx = blockIdx.x * blockDim.x + threadIdx.x;
    if (idx < 65536) {
        int out = idx >> 8, k = idx & 255;
        float v = (k < 128) ? Wl1[out * 128 + k] : Wr1[out * 128 + (k - 128)];
        int ks = k >> 5, quad = (k >> 3) & 3, e = k & 7, col = out & 15;
        int g = (out >> 4) * 8 + ks;
        W1s[(g * 64 + quad * 16 + col) * 8 + e] = f2bf(v);
    } else if (idx < 98304) {
        int i = idx - 65536; int out = i >> 8, k = i & 255;
        float v = (out < 64) ? Wl2[out * 256 + k] : Wr2[(out - 64) * 256 + k];
        int ks = k >> 5, quad = (k >> 3) & 3, e = k & 7, col = out & 15;
        int g = (out >> 4) * 8 + ks;
        W2s[(g * 64 + quad * 16 + col) * 8 + e] = f2bf(v);
    } else if (idx < 114688) {
        int i = idx - 98304;
        int out = i >> 6, k = i & 63;
        float v = fc1W[i];
        int ks = k >> 5, quad = (k >> 3) & 3, e = k & 7, col = out & 15;
        int g = (out >> 4) * 2 + ks;
        F1s[(g * 64 + quad * 16 + col) * 8 + e] = f2bf(v);
    } else if (idx < 147456) {
        int i = idx - 114688;
        int out = i >> 8, k = i & 255;
        float v = fc2W[i];
        int ks = k >> 5, quad = (k >> 3) & 3, e = k & 7, col = out & 15;
        int g = (out >> 4) * 8 + ks;
        F2s[(g * 64 + quad * 16 + col) * 8 + e] = f2bf(v);
    }
}

// x fp32 -> bf16 (packed pairs)
__global__ void convert_x(const float4* __restrict__ x4, uint2* __restrict__ xbf2, int total4) {
    int idx = blockIdx.x * blockDim.x + threadIdx.x;
    if (idx >= total4) return;
    float4 v = x4[idx];
    uint2 o;
    o.x = f2bf2(v.x, v.y);
    o.y = f2bf2(v.z, v.w);
    xbf2[idx] = o;
}

// ---------------- counting sort of edges by dst ----------------

__global__ void hist_kernel(const int* __restrict__ dst, int* __restrict__ degI, int E) {
    int e = blockIdx.x * blockDim.x + threadIdx.x;
    if (e >= E) return;
    atomicAdd(&degI[dst[e]], 1);
}

__global__ void scan_block(const int* __restrict__ degI, int* __restrict__ offs,
                           int* __restrict__ bsum, int N) {
    __shared__ int s[SCAN_B];
    int tid = threadIdx.x;
    int gid = blockIdx.x * SCAN_B + tid;
    int v = (gid < N) ? degI[gid] : 0;
    s[tid] = v;
    __syncthreads();
    for (int off = 1; off < SCAN_B; off <<= 1) {
        int t = (tid >= off) ? s[tid - off] : 0;
        __syncthreads();
        s[tid] += t;
        __syncthreads();
    }
    if (gid < N) offs[gid] = s[tid] - v;
    if (tid == SCAN_B - 1) bsum[blockIdx.x] = s[tid];
}

__global__ void scan_bsum(int* __restrict__ bsum, int nb) {
    __shared__ int s[128];
    int tid = threadIdx.x;
    int v = (tid < nb) ? bsum[tid] : 0;
    s[tid] = v;
    __syncthreads();
    for (int off = 1; off < 128; off <<= 1) {
        int t = (tid >= off) ? s[tid - off] : 0;
        __syncthreads();
        s[tid] += t;
        __syncthreads();
    }
    if (tid < nb) bsum[tid] = s[tid] - v;
}

__global__ void scan_add(int* __restrict__ offs, const int* __restrict__ bsum, int N) {
    int gid = blockIdx.x * SCAN_B + threadIdx.x;
    if (gid < N) offs[gid] += bsum[blockIdx.x];
}

// ---------------- two-pass radix partition (per-block reservation) ----------
// Pass 1: per-block LDS histogram over 196 buckets, ONE line-padded global
// atomicAdd per (block,bucket) to reserve space, then scatter packed
// (src | dlocal<<20) with LDS cursors. 1024 threads (16 waves) + 8-wide
// batched register loads: latency hidden by TLP+ILP, not serialized chains.
__global__ __launch_bounds__(RCR_T) void radix_count_reserve(
        const int* __restrict__ src, const int* __restrict__ dst,
        const int* __restrict__ offs, int* __restrict__ gcur,
        unsigned* __restrict__ pairs, int E) {
    __shared__ int hist[256];
    __shared__ int sBase[256];
    __shared__ int sCur[256];
    const int t = threadIdx.x;
    if (t < 256) { hist[t] = 0; sCur[t] = 0; }
    __syncthreads();
    const int e0 = blockIdx.x * CHUNK;

    if (e0 + CHUNK <= E) {
        // fast path: full chunk, compile-time-indexed register batches
        int dv[RCR_ILP], sv[RCR_ILP];
#pragma unroll
        for (int i = 0; i < RCR_ILP; i++) dv[i] = dst[e0 + t + i * RCR_T];
#pragma unroll
        for (int i = 0; i < RCR_ILP; i++) atomicAdd(&hist[dv[i] >> BSHIFT], 1);
        __syncthreads();
        if (t < NBUCK && hist[t] > 0)
            sBase[t] = offs[t << BSHIFT] + atomicAdd(&gcur[t * 16], hist[t]);
        __syncthreads();
#pragma unroll
        for (int i = 0; i < RCR_ILP; i++) sv[i] = src[e0 + t + i * RCR_T];
#pragma unroll
        for (int i = 0; i < RCR_ILP; i++) {
            int d = dv[i];
            int b = d >> BSHIFT;
            int pos = sBase[b] + atomicAdd(&sCur[b], 1);
            pairs[pos] = (unsigned)sv[i] | ((unsigned)(d & 511) << 20);
        }
    } else {
        // tail chunk
        const int e1 = E;
        for (int e = e0 + t; e < e1; e += RCR_T)
            atomicAdd(&hist[dst[e] >> BSHIFT], 1);
        __syncthreads();
        if (t < NBUCK && hist[t] > 0)
            sBase[t] = offs[t << BSHIFT] + atomicAdd(&gcur[t * 16], hist[t]);
        __syncthreads();
        for (int e = e0 + t; e < e1; e += RCR_T) {
            int d = dst[e];
            int b = d >> BSHIFT;
            int pos = sBase[b] + atomicAdd(&sCur[b], 1);
            pairs[pos] = (unsigned)src[e] | ((unsigned)(d & 511) << 20);
        }
    }
}

// Pass 2: one WG per bucket; sequential read of its ~32KB pair slice, scatter
// into its ~32KB srcS window via LDS cursors (no global atomics; L2-resident).
// 512 threads + 4-wide batched pair loads.
__global__ __launch_bounds__(512) void radix_scatter(
        const unsigned* __restrict__ pairs, const int* __restrict__ offs,
        int* __restrict__ srcS, int E) {
    __shared__ int sOffs[512];
    __shared__ int sCur[512];
    const int b = blockIdx.x;
    const int lo = b << BSHIFT;
    const int t = threadIdx.x;
    {
        int node = lo + t;
        sOffs[t] = (node < N_NODES) ? offs[node] : E;
        sCur[t] = 0;
    }
    __syncthreads();
    const int start = sOffs[0];
    const int endNode = lo + 512;
    const int end = (endNode < N_NODES) ? offs[endNode] : E;
    int i = start + t;
    for (; i + 3 * 512 < end; i += 4 * 512) {
        unsigned p0 = pairs[i];
        unsigned p1 = pairs[i + 512];
        unsigned p2 = pairs[i + 1024];
        unsigned p3 = pairs[i + 1536];
        int dl0 = (int)(p0 >> 20), dl1 = (int)(p1 >> 20);
        int dl2 = (int)(p2 >> 20), dl3 = (int)(p3 >> 20);
        int q0 = sOffs[dl0] + atomicAdd(&sCur[dl0], 1);
        int q1 = sOffs[dl1] + atomicAdd(&sCur[dl1], 1);
        int q2 = sOffs[dl2] + atomicAdd(&sCur[dl2], 1);
        int q3 = sOffs[dl3] + atomicAdd(&sCur[dl3], 1);
        srcS[q0] = (int)(p0 & 0xFFFFFu);
        srcS[q1] = (int)(p1 & 0xFFFFFu);
        srcS[q2] = (int)(p2 & 0xFFFFFu);
        srcS[q3] = (int)(p3 & 0xFFFFFu);
    }
    for (; i < end; i += 512) {
        unsigned p = pairs[i];
        int dl = (int)(p >> 20);
        int pos = sOffs[dl] + atomicAdd(&sCur[dl], 1);
        srcS[pos] = (int)(p & 0xFFFFFu);
    }
}

// ---------------- gather: mean of bf16 x rows -> packed bf16 mean ----------------
// one wave per node; lane = uint = 2 features (128 feats total)
__global__ __launch_bounds__(256) void gather_mean_bf(
        const unsigned* __restrict__ xbfu, const int* __restrict__ srcS,
        const int* __restrict__ offs, const int* __restrict__ degI,
        unsigned* __restrict__ meanbf) {
    const int wave = threadIdx.x >> 6, lane = threadIdx.x & 63;
    const int n = blockIdx.x * 4 + wave;
    if (n >= N_NODES) return;
    const int start = offs[n], cnt = degI[n];
    const int* sp = srcS + start;
    float2 a0 = {0.f, 0.f}, a1 = {0.f, 0.f}, a2 = {0.f, 0.f}, a3 = {0.f, 0.f};
    float2 a4 = {0.f, 0.f}, a5 = {0.f, 0.f}, a6 = {0.f, 0.f}, a7 = {0.f, 0.f};
    int j = 0;
    for (; j + 8 <= cnt; j += 8) {
        unsigned v0 = xbfu[sp[j]     * 64 + lane];
        unsigned v1 = xbfu[sp[j + 1] * 64 + lane];
        unsigned v2 = xbfu[sp[j + 2] * 64 + lane];
        unsigned v3 = xbfu[sp[j + 3] * 64 + lane];
        unsigned v4 = xbfu[sp[j + 4] * 64 + lane];
        unsigned v5 = xbfu[sp[j + 5] * 64 + lane];
        unsigned v6 = xbfu[sp[j + 6] * 64 + lane];
        unsigned v7 = xbfu[sp[j + 7] * 64 + lane];
        float2 f0 = bf2f2(v0), f1 = bf2f2(v1), f2 = bf2f2(v2), f3 = bf2f2(v3);
        float2 f4 = bf2f2(v4), f5 = bf2f2(v5), f6 = bf2f2(v6), f7 = bf2f2(v7);
        a0.x += f0.x; a0.y += f0.y;  a1.x += f1.x; a1.y += f1.y;
        a2.x += f2.x; a2.y += f2.y;  a3.x += f3.x; a3.y += f3.y;
        a4.x += f4.x; a4.y += f4.y;  a5.x += f5.x; a5.y += f5.y;
        a6.x += f6.x; a6.y += f6.y;  a7.x += f7.x; a7.y += f7.y;
    }
    for (; j + 2 <= cnt; j += 2) {
        float2 f0 = bf2f2(xbfu[sp[j]     * 64 + lane]);
        float2 f1 = bf2f2(xbfu[sp[j + 1] * 64 + lane]);
        a0.x += f0.x; a0.y += f0.y;
        a1.x += f1.x; a1.y += f1.y;
    }
    if (j < cnt) {
        float2 f0 = bf2f2(xbfu[sp[j] * 64 + lane]);
        a0.x += f0.x; a0.y += f0.y;
    }
    float rd = 1.0f / fmaxf((float)cnt, 1.0f);
    float mx = ((a0.x + a1.x) + (a2.x + a3.x)) + ((a4.x + a5.x) + (a6.x + a7.x));
    float my = ((a0.y + a1.y) + (a2.y + a3.y)) + ((a4.y + a5.y) + (a6.y + a7.y));
    meanbf[n * 64 + lane] = f2bf2(mx * rd, my * rd);
}

// ---------------- layer1 MFMA: [mean|x] -> h -> [z2|r2] ----------------
__global__ __launch_bounds__(256, 4) void layer1_mfma(
        const unsigned* __restrict__ xbfu, const unsigned* __restrict__ meanbf,
        const unsigned short* __restrict__ W1s, const float* __restrict__ bl1,
        const unsigned short* __restrict__ W2s,
        unsigned short* __restrict__ z2bf, float* __restrict__ embOut) {
    __shared__ unsigned short sA[MT][264];
    __shared__ unsigned short sH[MT][264];
    const int tid = threadIdx.x;
    const int node0 = blockIdx.x * MT;

    // staging: 1024 x 16B chunks (mean -> cols 0:128, x -> cols 128:256)
    const uint4* mean4 = (const uint4*)meanbf;
    const uint4* x4    = (const uint4*)xbfu;
#pragma unroll
    for (int it = 0; it < 4; it++) {
        int c = tid + it * 256;
        int row = c >> 5, half = (c >> 4) & 1, ci = c & 15;
        uint4 v = half ? x4[(node0 + row) * 16 + ci]
                       : mean4[(node0 + row) * 16 + ci];
        *(uint4*)&sA[row][half * 128 + ci * 8] = v;
    }
    __syncthreads();

    const int wave = tid >> 6, lane = tid & 63;
    const int col = lane & 15, quad = lane >> 4;

    // ---- phase A: h = relu(A @ W1^T + bl1), N=256, K=256 ----
    floatx4 acc[2][4];
    const floatx4 zero = {0.f, 0.f, 0.f, 0.f};
#pragma unroll
    for (int mt = 0; mt < 2; mt++)
#pragma unroll
        for (int nt = 0; nt < 4; nt++) acc[mt][nt] = zero;

    const short8* w1base = (const short8*)W1s + wave * 2048 + lane;
#pragma unroll
    for (int ks = 0; ks < 8; ks++) {
        short8 a0 = *(const short8*)&sA[col][ks * 32 + quad * 8];
        short8 a1 = *(const short8*)&sA[16 + col][ks * 32 + quad * 8];
#pragma unroll
        for (int nt = 0; nt < 4; nt++) {
            short8 b = w1base[(nt * 8 + ks) * 64];
            acc[0][nt] = MFMA16(a0, b, acc[0][nt]);
            acc[1][nt] = MFMA16(a1, b, acc[1][nt]);
        }
    }

#pragma unroll
    for (int nt = 0; nt < 4; nt++) {
        int out = (wave * 4 + nt) * 16 + col;
        float bias = bl1[out];
#pragma unroll
        for (int mt = 0; mt < 2; mt++)
#pragma unroll
            for (int r = 0; r < 4; r++)
                sH[mt * 16 + quad * 4 + r][out] = f2bf(fmaxf(acc[mt][nt][r] + bias, 0.f));
    }
    __syncthreads();

    // ---- phase B: [z2|r2] = h @ W2^T, N=128, K=256 ----
    floatx4 acc2[2][2];
#pragma unroll
    for (int mt = 0; mt < 2; mt++)
#pragma unroll
        for (int nt = 0; nt < 2; nt++) acc2[mt][nt] = zero;

    const short8* w2base = (const short8*)W2s + wave * 1024 + lane;
#pragma unroll
    for (int ks = 0; ks < 8; ks++) {
        short8 h0 = *(const short8*)&sH[col][ks * 32 + quad * 8];
        short8 h1 = *(const short8*)&sH[16 + col][ks * 32 + quad * 8];
#pragma unroll
        for (int nt = 0; nt < 2; nt++) {
            short8 b = w2base[(nt * 8 + ks) * 64];
            acc2[0][nt] = MFMA16(h0, b, acc2[0][nt]);
            acc2[1][nt] = MFMA16(h1, b, acc2[1][nt]);
        }
    }

#pragma unroll
    for (int nt = 0; nt < 2; nt++) {
        int out = (wave * 2 + nt) * 16 + col;
#pragma unroll
        for (int mt = 0; mt < 2; mt++)
#pragma unroll
            for (int r = 0; r < 4; r++) {
                int node = node0 + mt * 16 + quad * 4 + r;
                float v = acc2[mt][nt][r];
                if (out < 64) z2bf[node * 64 + out] = f2bf(v);
                else          embOut[node * 64 + (out - 64)] = v;
            }
    }
}

// ---------------- gather: emb = agg(z2)/deg + bl2 + r2 ----------------
__global__ __launch_bounds__(256) void gather_emb(
        const unsigned* __restrict__ z2u, const int* __restrict__ srcS,
        const int* __restrict__ offs, const int* __restrict__ degI,
        const float* __restrict__ bl2, float* __restrict__ emb,
        unsigned* __restrict__ embbf) {
    const int wave = threadIdx.x >> 6, lane = threadIdx.x & 63;
    const int n = blockIdx.x * 4 + wave;
    if (n >= N_NODES) return;
    const int start = offs[n], cnt = degI[n];
    const int* sp = srcS + start;
    const int half = lane >> 5, l32 = lane & 31;
    float a0x = 0.f, a0y = 0.f, a1x = 0.f, a1y = 0.f;
    float a2x = 0.f, a2y = 0.f, a3x = 0.f, a3y = 0.f;
    int j = 0;
    for (; j + 8 <= cnt; j += 8) {
        unsigned v0 = z2u[sp[j + half]     * 32 + l32];
        unsigned v1 = z2u[sp[j + 2 + half] * 32 + l32];
        unsigned v2 = z2u[sp[j + 4 + half] * 32 + l32];
        unsigned v3 = z2u[sp[j + 6 + half] * 32 + l32];
        float2 f0 = bf2f2(v0), f1 = bf2f2(v1), f2 = bf2f2(v2), f3 = bf2f2(v3);
        a0x += f0.x; a0y += f0.y;  a1x += f1.x; a1y += f1.y;
        a2x += f2.x; a2y += f2.y;  a3x += f3.x; a3y += f3.y;
    }
    for (; j + 2 <= cnt; j += 2) {
        float2 f0 = bf2f2(z2u[sp[j + half] * 32 + l32]);
        a0x += f0.x; a0y += f0.y;
    }
    if ((cnt & 1) && half == 0) {
        float2 f0 = bf2f2(z2u[sp[cnt - 1] * 32 + l32]);
        a0x += f0.x; a0y += f0.y;
    }
    float ax = (a0x + a1x) + (a2x + a3x);
    float ay = (a0y + a1y) + (a2y + a3y);
    ax += __shfl_down(ax, 32);
    ay += __shfl_down(ay, 32);
    if (half == 0) {
        float rd = 1.0f / fmaxf((float)cnt, 1.0f);
        float2 r2v = *(const float2*)&emb[n * 64 + l32 * 2];
        float ex = ax * rd + bl2[l32 * 2]     + r2v.x;
        float ey = ay * rd + bl2[l32 * 2 + 1] + r2v.y;
        float2 ev = {ex, ey};
        *(float2*)&emb[n * 64 + l32 * 2] = ev;
        embbf[n * 32 + l32] = f2bf2(ex, ey);
    }
}

// ---------------- decoder MFMA: emb -> hid -> recon ----------------
__global__ __launch_bounds__(256, 4) void decoder_mfma(
        const unsigned* __restrict__ embbf,
        const unsigned short* __restrict__ F1s, const float* __restrict__ fc1b,
        const unsigned short* __restrict__ F2s, const float* __restrict__ fc2b,
        float* __restrict__ recon) {
    __shared__ unsigned short sE[MT][72];
    __shared__ unsigned short sH[MT][264];
    const int tid = threadIdx.x;
    const int node0 = blockIdx.x * MT;

    // staging: 256 x 16B chunks, 1 per thread
    {
        const uint4* e4 = (const uint4*)embbf;
        int row = tid >> 3, ci = tid & 7;
        *(uint4*)&sE[row][ci * 8] = e4[(node0 + row) * 8 + ci];
    }
    __syncthreads();

    const int wave = tid >> 6, lane = tid & 63;
    const int col = lane & 15, quad = lane >> 4;

    // ---- phase A: hid = relu(emb @ fc1^T + fc1b), N=256, K=64 ----
    floatx4 acc[2][4];
    const floatx4 zero = {0.f, 0.f, 0.f, 0.f};
#pragma unroll
    for (int mt = 0; mt < 2; mt++)
#pragma unroll
        for (int nt = 0; nt < 4; nt++) acc[mt][nt] = zero;

    const short8* f1base = (const short8*)F1s + wave * 512 + lane;
#pragma unroll
    for (int ks = 0; ks < 2; ks++) {
        short8 a0 = *(const short8*)&sE[col][ks * 32 + quad * 8];
        short8 a1 = *(const short8*)&sE[16 + col][ks * 32 + quad * 8];
#pragma unroll
        for (int nt = 0; nt < 4; nt++) {
            short8 b = f1base[(nt * 2 + ks) * 64];
            acc[0][nt] = MFMA16(a0, b, acc[0][nt]);
            acc[1][nt] = MFMA16(a1, b, acc[1][nt]);
        }
    }

#pragma unroll
    for (int nt = 0; nt < 4; nt++) {
        int out = (wave * 4 + nt) * 16 + col;
        float bias = fc1b[out];
#pragma unroll
        for (int mt = 0; mt < 2; mt++)
#pragma unroll
            for (int r = 0; r < 4; r++)
                sH[mt * 16 + quad * 4 + r][out] = f2bf(fmaxf(acc[mt][nt][r] + bias, 0.f));
    }
    __syncthreads();

    // ---- phase B: recon = hid @ fc2^T + fc2b, N=128, K=256 ----
    floatx4 acc2[2][2];
#pragma unroll
    for (int mt = 0; mt < 2; mt++)
#pragma unroll
        for (int nt = 0; nt < 2; nt++) acc2[mt][nt] = zero;

    const short8* f2base = (const short8*)F2s + wave * 1024 + lane;
#pragma unroll
    for (int ks = 0; ks < 8; ks++) {
        short8 h0 = *(const short8*)&sH[col][ks * 32 + quad * 8];
        short8 h1 = *(const short8*)&sH[16 + col][ks * 32 + quad * 8];
#pragma unroll
        for (int nt = 0; nt < 2; nt++) {
            short8 b = f2base[(nt * 8 + ks) * 64];
            acc2[0][nt] = MFMA16(h0, b, acc2[0][nt]);
            acc2[1][nt] = MFMA16(h1, b, acc2[1][nt]);
        }
    }

#pragma unroll
    for (int nt = 0; nt < 2; nt++) {
        int out = (wave * 2 + nt) * 16 + col;
        float bias = fc2b[out];
#pragma unroll
        for (int mt = 0; mt < 2; mt++)
#pragma unroll
            for (int r = 0; r < 4; r++) {
                int node = node0 + mt * 16 + quad * 4 + r;
                recon[node * 128 + out] = acc2[mt][nt][r] + bias;
            }
    }
}

extern "C" void kernel_launch(void* const* d_in, const int* in_sizes, int n_in,
                              void* d_out, int out_size, void* d_ws, size_t ws_size,
                              hipStream_t stream) {
    const float* x    = (const float*)d_in[0];
    const int*   ei   = (const int*)d_in[1];
    const int E = in_sizes[1] / 2;
    const int* src = ei;
    const int* dst = ei + E;
    const float* Wl1  = (const float*)d_in[2];
    const float* bl1  = (const float*)d_in[3];
    const float* Wr1  = (const float*)d_in[4];
    const float* Wl2  = (const float*)d_in[5];
    const float* bl2  = (const float*)d_in[6];
    const float* Wr2  = (const float*)d_in[7];
    const float* fc1W = (const float*)d_in[8];
    const float* fc1b = (const float*)d_in[9];
    const float* fc2W = (const float*)d_in[10];
    const float* fc2b = (const float*)d_in[11];

    float* out   = (float*)d_out;
    float* emb   = out;                           // N*64
    float* recon = out + (size_t)N_NODES * D_E;   // N*128

    // workspace layout (512-aligned offsets)
    char* ws = (char*)d_ws;
    unsigned short* xbf    = (unsigned short*)(ws);             // 25,600,000 B
    unsigned*       meanbf = (unsigned*)(ws + 25600000);        // 25,600,000 B
    unsigned short* z2bf   = (unsigned short*)(ws + 51200000);  // 12,800,000 B
    unsigned*       embbf  = (unsigned*)(ws + 64000000);        // 12,800,000 B
    int* degI   = (int*)(ws + 76800000);                        //    400,000 B
    int* offs   = (int*)(ws + 77200384);                        //    400,000 B
    int* gcur   = (int*)(ws + 77600768);                        // 196*64 B padded counters
    int* bsum   = (int*)(ws + 78001152);                        //        512 B
    int* srcS   = (int*)(ws + 78001664);                        //  6,400,000 B
    unsigned short* W1s = (unsigned short*)(ws + 84401664);     //    131,072 B
    unsigned short* W2s = (unsigned short*)(ws + 84532736);     //     65,536 B
    unsigned short* F1s = (unsigned short*)(ws + 84598272);     //     32,768 B
    unsigned short* F2s = (unsigned short*)(ws + 84631040);     //     65,536 B
    // end 84,696,576 B
    // pairs buffer (6.4MB) reuses the meanbf region: its lifetime ends before
    // gather_mean_bf writes meanbf.
    unsigned* pairs = (unsigned*)(ws + 25600000);

    hipMemsetAsync(degI, 0, (size_t)N_NODES * sizeof(int), stream);
    hipMemsetAsync(gcur, 0, (size_t)NBUCK * 16 * sizeof(int), stream);

    convert_weights<<<(147456 + 255) / 256, 256, 0, stream>>>(
        Wl1, Wr1, Wl2, Wr2, fc1W, fc2W, W1s, W2s, F1s, F2s);
    convert_x<<<(N_NODES * 32 + 255) / 256, 256, 0, stream>>>(
        (const float4*)x, (uint2*)xbf, N_NODES * 32);

    // counting sort of edges by dst (radix two-pass)
    hist_kernel<<<(E + 255) / 256, 256, 0, stream>>>(dst, degI, E);
    const int nScanBlocks = (N_NODES + SCAN_B - 1) / SCAN_B;  // 98
    scan_block<<<nScanBlocks, SCAN_B, 0, stream>>>(degI, offs, bsum, N_NODES);
    scan_bsum<<<1, 128, 0, stream>>>(bsum, nScanBlocks);
    scan_add<<<nScanBlocks, SCAN_B, 0, stream>>>(offs, bsum, N_NODES);
    radix_count_reserve<<<(E + CHUNK - 1) / CHUNK, RCR_T, 0, stream>>>(
        src, dst, offs, gcur, pairs, E);
    radix_scatter<<<NBUCK, 512, 0, stream>>>(pairs, offs, srcS, E);

    // layer 1
    gather_mean_bf<<<(N_NODES + 3) / 4, 256, 0, stream>>>(
        (const unsigned*)xbf, srcS, offs, degI, meanbf);
    layer1_mfma<<<N_NODES / MT, 256, 0, stream>>>(
        (const unsigned*)xbf, meanbf, W1s, bl1, W2s, z2bf, emb);

    // layer 2 aggregation + emb finalize
    gather_emb<<<(N_NODES + 3) / 4, 256, 0, stream>>>(
        (const unsigned*)z2bf, srcS, offs, degI, bl2, emb, embbf);

    // decoder
    decoder_mfma<<<N_NODES / MT, 256, 0, stream>>>(
        embbf, F1s, fc1b, F2s, fc2b, recon);
}

// Round 7
// 346.569 us; speedup vs baseline: 1.8288x; 1.1815x over previous
//
#include <hip/hip_runtime.h>
#include <hip/hip_bf16.h>

#define N_NODES 100000
#define D_IN 128
#define D_H 256
#define D_E 64
#define MT 32        // nodes per GEMM block
#define BSHIFT 9                                   // 512 nodes per bucket
#define NBUCK ((N_NODES + 511) >> BSHIFT)          // 196
#define CHUNK 8192                                 // edges per pass-1 block
#define RCR_T 1024                                 // pass-1 threads
#define RCR_ILP (CHUNK / RCR_T)                    // 8 edges per thread

typedef __attribute__((ext_vector_type(8))) short short8;
typedef __attribute__((ext_vector_type(4))) float floatx4;

__device__ inline unsigned short f2bf(float f) {
    union { float f; unsigned u; } v; v.f = f;
    unsigned r = v.u + 0x7FFF + ((v.u >> 16) & 1);
    return (unsigned short)(r >> 16);
}
__device__ inline unsigned f2bf2(float a, float b) {
    return (unsigned)f2bf(a) | ((unsigned)f2bf(b) << 16);
}
__device__ inline float2 bf2f2(unsigned v) {
    union { unsigned u; float f; } lo, hi;
    lo.u = v << 16;
    hi.u = v & 0xffff0000u;
    return make_float2(lo.f, hi.f);  // .x = lower-address bf16
}

#define MFMA16(a, b, c) __builtin_amdgcn_mfma_f32_16x16x32_bf16((a), (b), (c), 0, 0, 0)

// ---------------- weight pre-pack to bf16, SWIZZLED to MFMA fragment order ----
__global__ void convert_weights(const float* __restrict__ Wl1, const float* __restrict__ Wr1,
                                const float* __restrict__ Wl2, const float* __restrict__ Wr2,
                                const float* __restrict__ fc1W, const float* __restrict__ fc2W,
                                unsigned short* __restrict__ W1s, unsigned short* __restrict__ W2s,
                                unsigned short* __restrict__ F1s, unsigned short* __restrict__ F2s) {
    int idx = blockIdx.x * blockDim.x + threadIdx.x;
    if (idx < 65536) {
        int out = idx >> 8, k = idx & 255;
        float v = (k < 128) ? Wl1[out * 128 + k] : Wr1[out * 128 + (k - 128)];
        int ks = k >> 5, quad = (k >> 3) & 3, e = k & 7, col = out & 15;
        int g = (out >> 4) * 8 + ks;
        W1s[(g * 64 + quad * 16 + col) * 8 + e] = f2bf(v);
    } else if (idx < 98304) {
        int i = idx - 65536; int out = i >> 8, k = i & 255;
        float v = (out < 64) ? Wl2[out * 256 + k] : Wr2[(out - 64) * 256 + k];
        int ks = k >> 5, quad = (k >> 3) & 3, e = k & 7, col = out & 15;
        int g = (out >> 4) * 8 + ks;
        W2s[(g * 64 + quad * 16 + col) * 8 + e] = f2bf(v);
    } else if (idx < 114688) {
        int i = idx - 98304;
        int out = i >> 6, k = i & 63;
        float v = fc1W[i];
        int ks = k >> 5, quad = (k >> 3) & 3, e = k & 7, col = out & 15;
        int g = (out >> 4) * 2 + ks;
        F1s[(g * 64 + quad * 16 + col) * 8 + e] = f2bf(v);
    } else if (idx < 147456) {
        int i = idx - 114688;
        int out = i >> 8, k = i & 255;
        float v = fc2W[i];
        int ks = k >> 5, quad = (k >> 3) & 3, e = k & 7, col = out & 15;
        int g = (out >> 4) * 8 + ks;
        F2s[(g * 64 + quad * 16 + col) * 8 + e] = f2bf(v);
    }
}

// x fp32 -> bf16 (packed pairs)
__global__ void convert_x(const float4* __restrict__ x4, uint2* __restrict__ xbf2, int total4) {
    int idx = blockIdx.x * blockDim.x + threadIdx.x;
    if (idx >= total4) return;
    float4 v = x4[idx];
    uint2 o;
    o.x = f2bf2(v.x, v.y);
    o.y = f2bf2(v.z, v.w);
    xbf2[idx] = o;
}

// ---------------- bucket-level histogram (replaces per-node hist) ----------
// LDS histogram over 196 buckets; one padded global atomic per (block,bucket).
__global__ __launch_bounds__(RCR_T) void bucket_hist(
        const int* __restrict__ dst, int* __restrict__ bucketCnt, int E) {
    __shared__ int hist[256];
    const int t = threadIdx.x;
    if (t < 256) hist[t] = 0;
    __syncthreads();
    const int e0 = blockIdx.x * CHUNK;
    if (e0 + CHUNK <= E) {
        int dv[RCR_ILP];
#pragma unroll
        for (int i = 0; i < RCR_ILP; i++) dv[i] = dst[e0 + t + i * RCR_T];
#pragma unroll
        for (int i = 0; i < RCR_ILP; i++) atomicAdd(&hist[dv[i] >> BSHIFT], 1);
    } else {
        for (int e = e0 + t; e < E; e += RCR_T)
            atomicAdd(&hist[dst[e] >> BSHIFT], 1);
    }
    __syncthreads();
    if (t < NBUCK && hist[t] > 0) atomicAdd(&bucketCnt[t * 16], hist[t]);
}

// single-block exclusive scan of 196 bucket counts -> bucketOffs[0..196]
__global__ void bucket_scan(const int* __restrict__ bucketCnt,
                            int* __restrict__ bucketOffs) {
    __shared__ int s[256];
    int t = threadIdx.x;
    int v = (t < NBUCK) ? bucketCnt[t * 16] : 0;
    s[t] = v;
    __syncthreads();
    for (int off = 1; off < 256; off <<= 1) {
        int tv = (t >= off) ? s[t - off] : 0;
        __syncthreads();
        s[t] += tv;
        __syncthreads();
    }
    if (t < NBUCK) bucketOffs[t] = s[t] - v;
    if (t == NBUCK - 1) bucketOffs[NBUCK] = s[t];
}

// ---------------- two-pass radix partition (per-block reservation) ----------
// Pass 1: per-block LDS histogram over 196 buckets, ONE line-padded global
// atomicAdd per (block,bucket) to reserve space, then scatter packed
// (src | dlocal<<20) with LDS cursors.
__global__ __launch_bounds__(RCR_T) void radix_count_reserve(
        const int* __restrict__ src, const int* __restrict__ dst,
        const int* __restrict__ bucketOffs, int* __restrict__ gcur,
        unsigned* __restrict__ pairs, int E) {
    __shared__ int hist[256];
    __shared__ int sBase[256];
    __shared__ int sCur[256];
    const int t = threadIdx.x;
    if (t < 256) { hist[t] = 0; sCur[t] = 0; }
    __syncthreads();
    const int e0 = blockIdx.x * CHUNK;

    if (e0 + CHUNK <= E) {
        int dv[RCR_ILP], sv[RCR_ILP];
#pragma unroll
        for (int i = 0; i < RCR_ILP; i++) dv[i] = dst[e0 + t + i * RCR_T];
#pragma unroll
        for (int i = 0; i < RCR_ILP; i++) atomicAdd(&hist[dv[i] >> BSHIFT], 1);
        __syncthreads();
        if (t < NBUCK && hist[t] > 0)
            sBase[t] = bucketOffs[t] + atomicAdd(&gcur[t * 16], hist[t]);
        __syncthreads();
#pragma unroll
        for (int i = 0; i < RCR_ILP; i++) sv[i] = src[e0 + t + i * RCR_T];
#pragma unroll
        for (int i = 0; i < RCR_ILP; i++) {
            int d = dv[i];
            int b = d >> BSHIFT;
            int pos = sBase[b] + atomicAdd(&sCur[b], 1);
            pairs[pos] = (unsigned)sv[i] | ((unsigned)(d & 511) << 20);
        }
    } else {
        const int e1 = E;
        for (int e = e0 + t; e < e1; e += RCR_T)
            atomicAdd(&hist[dst[e] >> BSHIFT], 1);
        __syncthreads();
        if (t < NBUCK && hist[t] > 0)
            sBase[t] = bucketOffs[t] + atomicAdd(&gcur[t * 16], hist[t]);
        __syncthreads();
        for (int e = e0 + t; e < e1; e += RCR_T) {
            int d = dst[e];
            int b = d >> BSHIFT;
            int pos = sBase[b] + atomicAdd(&sCur[b], 1);
            pairs[pos] = (unsigned)src[e] | ((unsigned)(d & 511) << 20);
        }
    }
}

// Pass 2: one WG per bucket. LDS-histogram the 512 local dst's from the pair
// slice, LDS scan -> write degI/offs directly (coalesced), then scatter into
// the bucket's srcS window via LDS cursors (no global atomics; L2-resident).
__global__ __launch_bounds__(512) void radix_scatter2(
        const unsigned* __restrict__ pairs, const int* __restrict__ bucketOffs,
        int* __restrict__ degI, int* __restrict__ offs,
        int* __restrict__ srcS) {
    __shared__ int sCnt[512];
    __shared__ int sOff[512];
    const int b = blockIdx.x;
    const int lo = b << BSHIFT;
    const int t = threadIdx.x;
    sCnt[t] = 0;
    __syncthreads();
    const int start = bucketOffs[b];
    const int end = bucketOffs[b + 1];
    // local histogram of dlocal
    for (int i = start + t; i < end; i += 512)
        atomicAdd(&sCnt[pairs[i] >> 20], 1);
    __syncthreads();
    // exclusive scan of 512 counts
    int v = sCnt[t];
    sOff[t] = v;
    __syncthreads();
    for (int off = 1; off < 512; off <<= 1) {
        int tv = (t >= off) ? sOff[t - off] : 0;
        __syncthreads();
        sOff[t] += tv;
        __syncthreads();
    }
    int excl = sOff[t] - v;
    int node = lo + t;
    if (node < N_NODES) {
        degI[node] = v;
        offs[node] = start + excl;
    }
    __syncthreads();
    // reuse sCnt as write cursors
    sCnt[t] = start + excl;
    __syncthreads();
    int i = start + t;
    for (; i + 3 * 512 < end; i += 4 * 512) {
        unsigned p0 = pairs[i];
        unsigned p1 = pairs[i + 512];
        unsigned p2 = pairs[i + 1024];
        unsigned p3 = pairs[i + 1536];
        int dl0 = (int)(p0 >> 20), dl1 = (int)(p1 >> 20);
        int dl2 = (int)(p2 >> 20), dl3 = (int)(p3 >> 20);
        int q0 = atomicAdd(&sCnt[dl0], 1);
        int q1 = atomicAdd(&sCnt[dl1], 1);
        int q2 = atomicAdd(&sCnt[dl2], 1);
        int q3 = atomicAdd(&sCnt[dl3], 1);
        srcS[q0] = (int)(p0 & 0xFFFFFu);
        srcS[q1] = (int)(p1 & 0xFFFFFu);
        srcS[q2] = (int)(p2 & 0xFFFFFu);
        srcS[q3] = (int)(p3 & 0xFFFFFu);
    }
    for (; i < end; i += 512) {
        unsigned p = pairs[i];
        int dl = (int)(p >> 20);
        int pos = atomicAdd(&sCnt[dl], 1);
        srcS[pos] = (int)(p & 0xFFFFFu);
    }
}

// ---------------- gather: mean of bf16 x rows -> packed bf16 mean ----------------
// one wave per node; lane = uint = 2 features (128 feats total)
__global__ __launch_bounds__(256) void gather_mean_bf(
        const unsigned* __restrict__ xbfu, const int* __restrict__ srcS,
        const int* __restrict__ offs, const int* __restrict__ degI,
        unsigned* __restrict__ meanbf) {
    const int wave = threadIdx.x >> 6, lane = threadIdx.x & 63;
    const int n = blockIdx.x * 4 + wave;
    if (n >= N_NODES) return;
    const int start = offs[n], cnt = degI[n];
    const int* sp = srcS + start;
    float2 a0 = {0.f, 0.f}, a1 = {0.f, 0.f}, a2 = {0.f, 0.f}, a3 = {0.f, 0.f};
    float2 a4 = {0.f, 0.f}, a5 = {0.f, 0.f}, a6 = {0.f, 0.f}, a7 = {0.f, 0.f};
    int j = 0;
    for (; j + 8 <= cnt; j += 8) {
        unsigned v0 = xbfu[sp[j]     * 64 + lane];
        unsigned v1 = xbfu[sp[j + 1] * 64 + lane];
        unsigned v2 = xbfu[sp[j + 2] * 64 + lane];
        unsigned v3 = xbfu[sp[j + 3] * 64 + lane];
        unsigned v4 = xbfu[sp[j + 4] * 64 + lane];
        unsigned v5 = xbfu[sp[j + 5] * 64 + lane];
        unsigned v6 = xbfu[sp[j + 6] * 64 + lane];
        unsigned v7 = xbfu[sp[j + 7] * 64 + lane];
        float2 f0 = bf2f2(v0), f1 = bf2f2(v1), f2 = bf2f2(v2), f3 = bf2f2(v3);
        float2 f4 = bf2f2(v4), f5 = bf2f2(v5), f6 = bf2f2(v6), f7 = bf2f2(v7);
        a0.x += f0.x; a0.y += f0.y;  a1.x += f1.x; a1.y += f1.y;
        a2.x += f2.x; a2.y += f2.y;  a3.x += f3.x; a3.y += f3.y;
        a4.x += f4.x; a4.y += f4.y;  a5.x += f5.x; a5.y += f5.y;
        a6.x += f6.x; a6.y += f6.y;  a7.x += f7.x; a7.y += f7.y;
    }
    for (; j + 2 <= cnt; j += 2) {
        float2 f0 = bf2f2(xbfu[sp[j]     * 64 + lane]);
        float2 f1 = bf2f2(xbfu[sp[j + 1] * 64 + lane]);
        a0.x += f0.x; a0.y += f0.y;
        a1.x += f1.x; a1.y += f1.y;
    }
    if (j < cnt) {
        float2 f0 = bf2f2(xbfu[sp[j] * 64 + lane]);
        a0.x += f0.x; a0.y += f0.y;
    }
    float rd = 1.0f / fmaxf((float)cnt, 1.0f);
    float mx = ((a0.x + a1.x) + (a2.x + a3.x)) + ((a4.x + a5.x) + (a6.x + a7.x));
    float my = ((a0.y + a1.y) + (a2.y + a3.y)) + ((a4.y + a5.y) + (a6.y + a7.y));
    meanbf[n * 64 + lane] = f2bf2(mx * rd, my * rd);
}

// ---------------- layer1 MFMA: [mean|x] -> h -> [z2|r2] ----------------
__global__ __launch_bounds__(256, 4) void layer1_mfma(
        const unsigned* __restrict__ xbfu, const unsigned* __restrict__ meanbf,
        const unsigned short* __restrict__ W1s, const float* __restrict__ bl1,
        const unsigned short* __restrict__ W2s,
        unsigned short* __restrict__ z2bf, float* __restrict__ embOut) {
    __shared__ unsigned short sA[MT][264];
    __shared__ unsigned short sH[MT][264];
    const int tid = threadIdx.x;
    const int node0 = blockIdx.x * MT;

    // staging: 1024 x 16B chunks (mean -> cols 0:128, x -> cols 128:256)
    const uint4* mean4 = (const uint4*)meanbf;
    const uint4* x4    = (const uint4*)xbfu;
#pragma unroll
    for (int it = 0; it < 4; it++) {
        int c = tid + it * 256;
        int row = c >> 5, half = (c >> 4) & 1, ci = c & 15;
        uint4 v = half ? x4[(node0 + row) * 16 + ci]
                       : mean4[(node0 + row) * 16 + ci];
        *(uint4*)&sA[row][half * 128 + ci * 8] = v;
    }
    __syncthreads();

    const int wave = tid >> 6, lane = tid & 63;
    const int col = lane & 15, quad = lane >> 4;

    // ---- phase A: h = relu(A @ W1^T + bl1), N=256, K=256 ----
    floatx4 acc[2][4];
    const floatx4 zero = {0.f, 0.f, 0.f, 0.f};
#pragma unroll
    for (int mt = 0; mt < 2; mt++)
#pragma unroll
        for (int nt = 0; nt < 4; nt++) acc[mt][nt] = zero;

    const short8* w1base = (const short8*)W1s + wave * 2048 + lane;
#pragma unroll
    for (int ks = 0; ks < 8; ks++) {
        short8 a0 = *(const short8*)&sA[col][ks * 32 + quad * 8];
        short8 a1 = *(const short8*)&sA[16 + col][ks * 32 + quad * 8];
#pragma unroll
        for (int nt = 0; nt < 4; nt++) {
            short8 b = w1base[(nt * 8 + ks) * 64];
            acc[0][nt] = MFMA16(a0, b, acc[0][nt]);
            acc[1][nt] = MFMA16(a1, b, acc[1][nt]);
        }
    }

#pragma unroll
    for (int nt = 0; nt < 4; nt++) {
        int out = (wave * 4 + nt) * 16 + col;
        float bias = bl1[out];
#pragma unroll
        for (int mt = 0; mt < 2; mt++)
#pragma unroll
            for (int r = 0; r < 4; r++)
                sH[mt * 16 + quad * 4 + r][out] = f2bf(fmaxf(acc[mt][nt][r] + bias, 0.f));
    }
    __syncthreads();

    // ---- phase B: [z2|r2] = h @ W2^T, N=128, K=256 ----
    floatx4 acc2[2][2];
#pragma unroll
    for (int mt = 0; mt < 2; mt++)
#pragma unroll
        for (int nt = 0; nt < 2; nt++) acc2[mt][nt] = zero;

    const short8* w2base = (const short8*)W2s + wave * 1024 + lane;
#pragma unroll
    for (int ks = 0; ks < 8; ks++) {
        short8 h0 = *(const short8*)&sH[col][ks * 32 + quad * 8];
        short8 h1 = *(const short8*)&sH[16 + col][ks * 32 + quad * 8];
#pragma unroll
        for (int nt = 0; nt < 2; nt++) {
            short8 b = w2base[(nt * 8 + ks) * 64];
            acc2[0][nt] = MFMA16(h0, b, acc2[0][nt]);
            acc2[1][nt] = MFMA16(h1, b, acc2[1][nt]);
        }
    }

#pragma unroll
    for (int nt = 0; nt < 2; nt++) {
        int out = (wave * 2 + nt) * 16 + col;
#pragma unroll
        for (int mt = 0; mt < 2; mt++)
#pragma unroll
            for (int r = 0; r < 4; r++) {
                int node = node0 + mt * 16 + quad * 4 + r;
                float v = acc2[mt][nt][r];
                if (out < 64) z2bf[node * 64 + out] = f2bf(v);
                else          embOut[node * 64 + (out - 64)] = v;
            }
    }
}

// ---------------- gather: emb = agg(z2)/deg + bl2 + r2 ----------------
__global__ __launch_bounds__(256) void gather_emb(
        const unsigned* __restrict__ z2u, const int* __restrict__ srcS,
        const int* __restrict__ offs, const int* __restrict__ degI,
        const float* __restrict__ bl2, float* __restrict__ emb,
        unsigned* __restrict__ embbf) {
    const int wave = threadIdx.x >> 6, lane = threadIdx.x & 63;
    const int n = blockIdx.x * 4 + wave;
    if (n >= N_NODES) return;
    const int start = offs[n], cnt = degI[n];
    const int* sp = srcS + start;
    const int half = lane >> 5, l32 = lane & 31;
    float a0x = 0.f, a0y = 0.f, a1x = 0.f, a1y = 0.f;
    float a2x = 0.f, a2y = 0.f, a3x = 0.f, a3y = 0.f;
    int j = 0;
    for (; j + 8 <= cnt; j += 8) {
        unsigned v0 = z2u[sp[j + half]     * 32 + l32];
        unsigned v1 = z2u[sp[j + 2 + half] * 32 + l32];
        unsigned v2 = z2u[sp[j + 4 + half] * 32 + l32];
        unsigned v3 = z2u[sp[j + 6 + half] * 32 + l32];
        float2 f0 = bf2f2(v0), f1 = bf2f2(v1), f2 = bf2f2(v2), f3 = bf2f2(v3);
        a0x += f0.x; a0y += f0.y;  a1x += f1.x; a1y += f1.y;
        a2x += f2.x; a2y += f2.y;  a3x += f3.x; a3y += f3.y;
    }
    for (; j + 2 <= cnt; j += 2) {
        float2 f0 = bf2f2(z2u[sp[j + half] * 32 + l32]);
        a0x += f0.x; a0y += f0.y;
    }
    if ((cnt & 1) && half == 0) {
        float2 f0 = bf2f2(z2u[sp[cnt - 1] * 32 + l32]);
        a0x += f0.x; a0y += f0.y;
    }
    float ax = (a0x + a1x) + (a2x + a3x);
    float ay = (a0y + a1y) + (a2y + a3y);
    ax += __shfl_down(ax, 32);
    ay += __shfl_down(ay, 32);
    if (half == 0) {
        float rd = 1.0f / fmaxf((float)cnt, 1.0f);
        float2 r2v = *(const float2*)&emb[n * 64 + l32 * 2];
        float ex = ax * rd + bl2[l32 * 2]     + r2v.x;
        float ey = ay * rd + bl2[l32 * 2 + 1] + r2v.y;
        float2 ev = {ex, ey};
        *(float2*)&emb[n * 64 + l32 * 2] = ev;
        embbf[n * 32 + l32] = f2bf2(ex, ey);
    }
}

// ---------------- decoder MFMA: emb -> hid -> recon ----------------
__global__ __launch_bounds__(256, 4) void decoder_mfma(
        const unsigned* __restrict__ embbf,
        const unsigned short* __restrict__ F1s, const float* __restrict__ fc1b,
        const unsigned short* __restrict__ F2s, const float* __restrict__ fc2b,
        float* __restrict__ recon) {
    __shared__ unsigned short sE[MT][72];
    __shared__ unsigned short sH[MT][264];
    const int tid = threadIdx.x;
    const int node0 = blockIdx.x * MT;

    // staging: 256 x 16B chunks, 1 per thread
    {
        const uint4* e4 = (const uint4*)embbf;
        int row = tid >> 3, ci = tid & 7;
        *(uint4*)&sE[row][ci * 8] = e4[(node0 + row) * 8 + ci];
    }
    __syncthreads();

    const int wave = tid >> 6, lane = tid & 63;
    const int col = lane & 15, quad = lane >> 4;

    // ---- phase A: hid = relu(emb @ fc1^T + fc1b), N=256, K=64 ----
    floatx4 acc[2][4];
    const floatx4 zero = {0.f, 0.f, 0.f, 0.f};
#pragma unroll
    for (int mt = 0; mt < 2; mt++)
#pragma unroll
        for (int nt = 0; nt < 4; nt++) acc[mt][nt] = zero;

    const short8* f1base = (const short8*)F1s + wave * 512 + lane;
#pragma unroll
    for (int ks = 0; ks < 2; ks++) {
        short8 a0 = *(const short8*)&sE[col][ks * 32 + quad * 8];
        short8 a1 = *(const short8*)&sE[16 + col][ks * 32 + quad * 8];
#pragma unroll
        for (int nt = 0; nt < 4; nt++) {
            short8 b = f1base[(nt * 2 + ks) * 64];
            acc[0][nt] = MFMA16(a0, b, acc[0][nt]);
            acc[1][nt] = MFMA16(a1, b, acc[1][nt]);
        }
    }

#pragma unroll
    for (int nt = 0; nt < 4; nt++) {
        int out = (wave * 4 + nt) * 16 + col;
        float bias = fc1b[out];
#pragma unroll
        for (int mt = 0; mt < 2; mt++)
#pragma unroll
            for (int r = 0; r < 4; r++)
                sH[mt * 16 + quad * 4 + r][out] = f2bf(fmaxf(acc[mt][nt][r] + bias, 0.f));
    }
    __syncthreads();

    // ---- phase B: recon = hid @ fc2^T + fc2b, N=128, K=256 ----
    floatx4 acc2[2][2];
#pragma unroll
    for (int mt = 0; mt < 2; mt++)
#pragma unroll
        for (int nt = 0; nt < 2; nt++) acc2[mt][nt] = zero;

    const short8* f2base = (const short8*)F2s + wave * 1024 + lane;
#pragma unroll
    for (int ks = 0; ks < 8; ks++) {
        short8 h0 = *(const short8*)&sH[col][ks * 32 + quad * 8];
        short8 h1 = *(const short8*)&sH[16 + col][ks * 32 + quad * 8];
#pragma unroll
        for (int nt = 0; nt < 2; nt++) {
            short8 b = f2base[(nt * 8 + ks) * 64];
            acc2[0][nt] = MFMA16(h0, b, acc2[0][nt]);
            acc2[1][nt] = MFMA16(h1, b, acc2[1][nt]);
        }
    }

#pragma unroll
    for (int nt = 0; nt < 2; nt++) {
        int out = (wave * 2 + nt) * 16 + col;
        float bias = fc2b[out];
#pragma unroll
        for (int mt = 0; mt < 2; mt++)
#pragma unroll
            for (int r = 0; r < 4; r++) {
                int node = node0 + mt * 16 + quad * 4 + r;
                recon[node * 128 + out] = acc2[mt][nt][r] + bias;
            }
    }
}

extern "C" void kernel_launch(void* const* d_in, const int* in_sizes, int n_in,
                              void* d_out, int out_size, void* d_ws, size_t ws_size,
                              hipStream_t stream) {
    const float* x    = (const float*)d_in[0];
    const int*   ei   = (const int*)d_in[1];
    const int E = in_sizes[1] / 2;
    const int* src = ei;
    const int* dst = ei + E;
    const float* Wl1  = (const float*)d_in[2];
    const float* bl1  = (const float*)d_in[3];
    const float* Wr1  = (const float*)d_in[4];
    const float* Wl2  = (const float*)d_in[5];
    const float* bl2  = (const float*)d_in[6];
    const float* Wr2  = (const float*)d_in[7];
    const float* fc1W = (const float*)d_in[8];
    const float* fc1b = (const float*)d_in[9];
    const float* fc2W = (const float*)d_in[10];
    const float* fc2b = (const float*)d_in[11];

    float* out   = (float*)d_out;
    float* emb   = out;                           // N*64
    float* recon = out + (size_t)N_NODES * D_E;   // N*128

    // workspace layout (512-aligned offsets)
    char* ws = (char*)d_ws;
    unsigned short* xbf    = (unsigned short*)(ws);             // 25,600,000 B
    unsigned*       meanbf = (unsigned*)(ws + 25600000);        // 25,600,000 B
    unsigned short* z2bf   = (unsigned short*)(ws + 51200000);  // 12,800,000 B
    unsigned*       embbf  = (unsigned*)(ws + 64000000);        // 12,800,000 B
    int* degI   = (int*)(ws + 76800000);                        //    400,000 B
    int* offs   = (int*)(ws + 77200384);                        //    400,000 B
    int* gcur      = (int*)(ws + 77600768);                     // 196*64 B padded counters
    int* bucketCnt = (int*)(ws + 77617152);                     // 196*64 B padded counters
    int* bucketOffs= (int*)(ws + 77633536);                     // 197*4 B
    int* srcS   = (int*)(ws + 78001664);                        //  6,400,000 B
    unsigned short* W1s = (unsigned short*)(ws + 84401664);     //    131,072 B
    unsigned short* W2s = (unsigned short*)(ws + 84532736);     //     65,536 B
    unsigned short* F1s = (unsigned short*)(ws + 84598272);     //     32,768 B
    unsigned short* F2s = (unsigned short*)(ws + 84631040);     //     65,536 B
    // end 84,696,576 B
    // pairs buffer (6.4MB) reuses the meanbf region: its lifetime ends before
    // gather_mean_bf writes meanbf.
    unsigned* pairs = (unsigned*)(ws + 25600000);

    // gcur + bucketCnt are contiguous: one memset
    hipMemsetAsync(gcur, 0, 32768, stream);

    convert_weights<<<(147456 + 255) / 256, 256, 0, stream>>>(
        Wl1, Wr1, Wl2, Wr2, fc1W, fc2W, W1s, W2s, F1s, F2s);
    convert_x<<<(N_NODES * 32 + 255) / 256, 256, 0, stream>>>(
        (const float4*)x, (uint2*)xbf, N_NODES * 32);

    // counting sort of edges by dst (bucket hist + radix two-pass;
    // per-node degI/offs produced inside radix_scatter2)
    const int nChunks = (E + CHUNK - 1) / CHUNK;  // 196 at E=1.6M
    bucket_hist<<<nChunks, RCR_T, 0, stream>>>(dst, bucketCnt, E);
    bucket_scan<<<1, 256, 0, stream>>>(bucketCnt, bucketOffs);
    radix_count_reserve<<<nChunks, RCR_T, 0, stream>>>(
        src, dst, bucketOffs, gcur, pairs, E);
    radix_scatter2<<<NBUCK, 512, 0, stream>>>(
        pairs, bucketOffs, degI, offs, srcS);

    // layer 1
    gather_mean_bf<<<(N_NODES + 3) / 4, 256, 0, stream>>>(
        (const unsigned*)xbf, srcS, offs, degI, meanbf);
    layer1_mfma<<<N_NODES / MT, 256, 0, stream>>>(
        (const unsigned*)xbf, meanbf, W1s, bl1, W2s, z2bf, emb);

    // layer 2 aggregation + emb finalize
    gather_emb<<<(N_NODES + 3) / 4, 256, 0, stream>>>(
        (const unsigned*)z2bf, srcS, offs, degI, bl2, emb, embbf);

    // decoder
    decoder_mfma<<<N_NODES / MT, 256, 0, stream>>>(
        embbf, F1s, fc1b, F2s, fc2b, recon);
}

// Round 8
// 333.415 us; speedup vs baseline: 1.9010x; 1.0395x over previous
//
#include <hip/hip_runtime.h>
#include <hip/hip_bf16.h>

#define N_NODES 100000
#define D_IN 128
#define D_H 256
#define D_E 64
#define MT 32        // nodes per GEMM block
#define BSHIFT 9                                   // 512 nodes per bucket
#define NBUCK ((N_NODES + 511) >> BSHIFT)          // 196
#define CHUNK 8192                                 // edges per pass-1 block
#define RCR_T 1024                                 // pass-1 threads
#define RCR_ILP (CHUNK / RCR_T)                    // 8 edges per thread

typedef __attribute__((ext_vector_type(8))) short short8;
typedef __attribute__((ext_vector_type(4))) float floatx4;

__device__ inline unsigned short f2bf(float f) {
    union { float f; unsigned u; } v; v.f = f;
    unsigned r = v.u + 0x7FFF + ((v.u >> 16) & 1);
    return (unsigned short)(r >> 16);
}
__device__ inline unsigned f2bf2(float a, float b) {
    return (unsigned)f2bf(a) | ((unsigned)f2bf(b) << 16);
}
__device__ inline float2 bf2f2(unsigned v) {
    union { unsigned u; float f; } lo, hi;
    lo.u = v << 16;
    hi.u = v & 0xffff0000u;
    return make_float2(lo.f, hi.f);  // .x = lower-address bf16
}

#define MFMA16(a, b, c) __builtin_amdgcn_mfma_f32_16x16x32_bf16((a), (b), (c), 0, 0, 0)

// ---------------- weight pre-pack to bf16, SWIZZLED to MFMA fragment order ----
__global__ void convert_weights(const float* __restrict__ Wl1, const float* __restrict__ Wr1,
                                const float* __restrict__ Wl2, const float* __restrict__ Wr2,
                                const float* __restrict__ fc1W, const float* __restrict__ fc2W,
                                unsigned short* __restrict__ W1s, unsigned short* __restrict__ W2s,
                                unsigned short* __restrict__ F1s, unsigned short* __restrict__ F2s) {
    int idx = blockIdx.x * blockDim.x + threadIdx.x;
    if (idx < 65536) {
        int out = idx >> 8, k = idx & 255;
        float v = (k < 128) ? Wl1[out * 128 + k] : Wr1[out * 128 + (k - 128)];
        int ks = k >> 5, quad = (k >> 3) & 3, e = k & 7, col = out & 15;
        int g = (out >> 4) * 8 + ks;
        W1s[(g * 64 + quad * 16 + col) * 8 + e] = f2bf(v);
    } else if (idx < 98304) {
        int i = idx - 65536; int out = i >> 8, k = i & 255;
        float v = (out < 64) ? Wl2[out * 256 + k] : Wr2[(out - 64) * 256 + k];
        int ks = k >> 5, quad = (k >> 3) & 3, e = k & 7, col = out & 15;
        int g = (out >> 4) * 8 + ks;
        W2s[(g * 64 + quad * 16 + col) * 8 + e] = f2bf(v);
    } else if (idx < 114688) {
        int i = idx - 98304;
        int out = i >> 6, k = i & 63;
        float v = fc1W[i];
        int ks = k >> 5, quad = (k >> 3) & 3, e = k & 7, col = out & 15;
        int g = (out >> 4) * 2 + ks;
        F1s[(g * 64 + quad * 16 + col) * 8 + e] = f2bf(v);
    } else if (idx < 147456) {
        int i = idx - 114688;
        int out = i >> 8, k = i & 255;
        float v = fc2W[i];
        int ks = k >> 5, quad = (k >> 3) & 3, e = k & 7, col = out & 15;
        int g = (out >> 4) * 8 + ks;
        F2s[(g * 64 + quad * 16 + col) * 8 + e] = f2bf(v);
    }
}

// x fp32 -> bf16 (packed pairs)
__global__ void convert_x(const float4* __restrict__ x4, uint2* __restrict__ xbf2, int total4) {
    int idx = blockIdx.x * blockDim.x + threadIdx.x;
    if (idx >= total4) return;
    float4 v = x4[idx];
    uint2 o;
    o.x = f2bf2(v.x, v.y);
    o.y = f2bf2(v.z, v.w);
    xbf2[idx] = o;
}

// ---------------- bucket-level histogram ----------
__global__ __launch_bounds__(RCR_T) void bucket_hist(
        const int* __restrict__ dst, int* __restrict__ bucketCnt, int E) {
    __shared__ int hist[256];
    const int t = threadIdx.x;
    if (t < 256) hist[t] = 0;
    __syncthreads();
    const int e0 = blockIdx.x * CHUNK;
    if (e0 + CHUNK <= E) {
        int dv[RCR_ILP];
#pragma unroll
        for (int i = 0; i < RCR_ILP; i++) dv[i] = dst[e0 + t + i * RCR_T];
#pragma unroll
        for (int i = 0; i < RCR_ILP; i++) atomicAdd(&hist[dv[i] >> BSHIFT], 1);
    } else {
        for (int e = e0 + t; e < E; e += RCR_T)
            atomicAdd(&hist[dst[e] >> BSHIFT], 1);
    }
    __syncthreads();
    if (t < NBUCK && hist[t] > 0) atomicAdd(&bucketCnt[t * 16], hist[t]);
}

// single-block exclusive scan of 196 bucket counts -> bucketOffs[0..196]
__global__ void bucket_scan(const int* __restrict__ bucketCnt,
                            int* __restrict__ bucketOffs) {
    __shared__ int s[256];
    int t = threadIdx.x;
    int v = (t < NBUCK) ? bucketCnt[t * 16] : 0;
    s[t] = v;
    __syncthreads();
    for (int off = 1; off < 256; off <<= 1) {
        int tv = (t >= off) ? s[t - off] : 0;
        __syncthreads();
        s[t] += tv;
        __syncthreads();
    }
    if (t < NBUCK) bucketOffs[t] = s[t] - v;
    if (t == NBUCK - 1) bucketOffs[NBUCK] = s[t];
}

// ---------------- two-pass radix partition (per-block reservation) ----------
__global__ __launch_bounds__(RCR_T) void radix_count_reserve(
        const int* __restrict__ src, const int* __restrict__ dst,
        const int* __restrict__ bucketOffs, int* __restrict__ gcur,
        unsigned* __restrict__ pairs, int E) {
    __shared__ int hist[256];
    __shared__ int sBase[256];
    __shared__ int sCur[256];
    const int t = threadIdx.x;
    if (t < 256) { hist[t] = 0; sCur[t] = 0; }
    __syncthreads();
    const int e0 = blockIdx.x * CHUNK;

    if (e0 + CHUNK <= E) {
        int dv[RCR_ILP], sv[RCR_ILP];
#pragma unroll
        for (int i = 0; i < RCR_ILP; i++) dv[i] = dst[e0 + t + i * RCR_T];
#pragma unroll
        for (int i = 0; i < RCR_ILP; i++) atomicAdd(&hist[dv[i] >> BSHIFT], 1);
        __syncthreads();
        if (t < NBUCK && hist[t] > 0)
            sBase[t] = bucketOffs[t] + atomicAdd(&gcur[t * 16], hist[t]);
        __syncthreads();
#pragma unroll
        for (int i = 0; i < RCR_ILP; i++) sv[i] = src[e0 + t + i * RCR_T];
#pragma unroll
        for (int i = 0; i < RCR_ILP; i++) {
            int d = dv[i];
            int b = d >> BSHIFT;
            int pos = sBase[b] + atomicAdd(&sCur[b], 1);
            pairs[pos] = (unsigned)sv[i] | ((unsigned)(d & 511) << 20);
        }
    } else {
        const int e1 = E;
        for (int e = e0 + t; e < e1; e += RCR_T)
            atomicAdd(&hist[dst[e] >> BSHIFT], 1);
        __syncthreads();
        if (t < NBUCK && hist[t] > 0)
            sBase[t] = bucketOffs[t] + atomicAdd(&gcur[t * 16], hist[t]);
        __syncthreads();
        for (int e = e0 + t; e < e1; e += RCR_T) {
            int d = dst[e];
            int b = d >> BSHIFT;
            int pos = sBase[b] + atomicAdd(&sCur[b], 1);
            pairs[pos] = (unsigned)src[e] | ((unsigned)(d & 511) << 20);
        }
    }
}

// Pass 2: one WG per bucket. LDS-histogram the 512 local dst's, LDS scan ->
// write degI/offs directly, then scatter into the bucket's srcS window.
__global__ __launch_bounds__(512) void radix_scatter2(
        const unsigned* __restrict__ pairs, const int* __restrict__ bucketOffs,
        int* __restrict__ degI, int* __restrict__ offs,
        int* __restrict__ srcS) {
    __shared__ int sCnt[512];
    __shared__ int sOff[512];
    const int b = blockIdx.x;
    const int lo = b << BSHIFT;
    const int t = threadIdx.x;
    sCnt[t] = 0;
    __syncthreads();
    const int start = bucketOffs[b];
    const int end = bucketOffs[b + 1];
    for (int i = start + t; i < end; i += 512)
        atomicAdd(&sCnt[pairs[i] >> 20], 1);
    __syncthreads();
    int v = sCnt[t];
    sOff[t] = v;
    __syncthreads();
    for (int off = 1; off < 512; off <<= 1) {
        int tv = (t >= off) ? sOff[t - off] : 0;
        __syncthreads();
        sOff[t] += tv;
        __syncthreads();
    }
    int excl = sOff[t] - v;
    int node = lo + t;
    if (node < N_NODES) {
        degI[node] = v;
        offs[node] = start + excl;
    }
    __syncthreads();
    sCnt[t] = start + excl;
    __syncthreads();
    int i = start + t;
    for (; i + 3 * 512 < end; i += 4 * 512) {
        unsigned p0 = pairs[i];
        unsigned p1 = pairs[i + 512];
        unsigned p2 = pairs[i + 1024];
        unsigned p3 = pairs[i + 1536];
        int dl0 = (int)(p0 >> 20), dl1 = (int)(p1 >> 20);
        int dl2 = (int)(p2 >> 20), dl3 = (int)(p3 >> 20);
        int q0 = atomicAdd(&sCnt[dl0], 1);
        int q1 = atomicAdd(&sCnt[dl1], 1);
        int q2 = atomicAdd(&sCnt[dl2], 1);
        int q3 = atomicAdd(&sCnt[dl3], 1);
        srcS[q0] = (int)(p0 & 0xFFFFFu);
        srcS[q1] = (int)(p1 & 0xFFFFFu);
        srcS[q2] = (int)(p2 & 0xFFFFFu);
        srcS[q3] = (int)(p3 & 0xFFFFFu);
    }
    for (; i < end; i += 512) {
        unsigned p = pairs[i];
        int dl = (int)(p >> 20);
        int pos = atomicAdd(&sCnt[dl], 1);
        srcS[pos] = (int)(p & 0xFFFFFu);
    }
}

// ---------------- gather: mean of bf16 x rows -> packed bf16 mean ------------
// one wave per node, QUARTER-WAVE per edge: 16 lanes x uint4 (16B) = 256B row.
// 4 edges per load instruction, 16 edges in flight per main iteration.
#define ACC8(v)                                                   \
    { float2 f_;                                                  \
      f_ = bf2f2((v).x); s0 += f_.x; s1 += f_.y;                  \
      f_ = bf2f2((v).y); s2 += f_.x; s3 += f_.y;                  \
      f_ = bf2f2((v).z); s4 += f_.x; s5 += f_.y;                  \
      f_ = bf2f2((v).w); s6 += f_.x; s7 += f_.y; }

__global__ __launch_bounds__(256) void gather_mean_bf(
        const uint4* __restrict__ xb4, const int* __restrict__ srcS,
        const int* __restrict__ offs, const int* __restrict__ degI,
        uint4* __restrict__ mean4) {
    const int wave = threadIdx.x >> 6, lane = threadIdx.x & 63;
    const int n = blockIdx.x * 4 + wave;
    if (n >= N_NODES) return;
    const int start = offs[n], cnt = degI[n];
    const int* sp = srcS + start;
    const int q = lane >> 4, l16 = lane & 15;
    float s0 = 0.f, s1 = 0.f, s2 = 0.f, s3 = 0.f;
    float s4 = 0.f, s5 = 0.f, s6 = 0.f, s7 = 0.f;
    int j = 0;
    for (; j + 16 <= cnt; j += 16) {
        int i0 = sp[j + q], i1 = sp[j + 4 + q];
        int i2 = sp[j + 8 + q], i3 = sp[j + 12 + q];
        uint4 v0 = xb4[i0 * 16 + l16];
        uint4 v1 = xb4[i1 * 16 + l16];
        uint4 v2 = xb4[i2 * 16 + l16];
        uint4 v3 = xb4[i3 * 16 + l16];
        ACC8(v0); ACC8(v1); ACC8(v2); ACC8(v3);
    }
    for (; j + 4 <= cnt; j += 4) {
        uint4 v = xb4[sp[j + q] * 16 + l16];
        ACC8(v);
    }
    if (q < cnt - j) {
        uint4 v = xb4[sp[j + q] * 16 + l16];
        ACC8(v);
    }
    // cross-quarter reduction: lanes 0-15 end with full sums
    s0 += __shfl_down(s0, 32); s1 += __shfl_down(s1, 32);
    s2 += __shfl_down(s2, 32); s3 += __shfl_down(s3, 32);
    s4 += __shfl_down(s4, 32); s5 += __shfl_down(s5, 32);
    s6 += __shfl_down(s6, 32); s7 += __shfl_down(s7, 32);
    s0 += __shfl_down(s0, 16); s1 += __shfl_down(s1, 16);
    s2 += __shfl_down(s2, 16); s3 += __shfl_down(s3, 16);
    s4 += __shfl_down(s4, 16); s5 += __shfl_down(s5, 16);
    s6 += __shfl_down(s6, 16); s7 += __shfl_down(s7, 16);
    if (lane < 16) {
        float rd = 1.0f / fmaxf((float)cnt, 1.0f);
        uint4 o;
        o.x = f2bf2(s0 * rd, s1 * rd);
        o.y = f2bf2(s2 * rd, s3 * rd);
        o.z = f2bf2(s4 * rd, s5 * rd);
        o.w = f2bf2(s6 * rd, s7 * rd);
        mean4[n * 16 + l16] = o;
    }
}

// ---------------- layer1 MFMA: [mean|x] -> h -> [z2|r2] ----------------
__global__ __launch_bounds__(256, 4) void layer1_mfma(
        const unsigned* __restrict__ xbfu, const unsigned* __restrict__ meanbf,
        const unsigned short* __restrict__ W1s, const float* __restrict__ bl1,
        const unsigned short* __restrict__ W2s,
        unsigned short* __restrict__ z2bf, float* __restrict__ embOut) {
    __shared__ unsigned short sA[MT][264];
    __shared__ unsigned short sH[MT][264];
    const int tid = threadIdx.x;
    const int node0 = blockIdx.x * MT;

    const uint4* mean4 = (const uint4*)meanbf;
    const uint4* x4    = (const uint4*)xbfu;
#pragma unroll
    for (int it = 0; it < 4; it++) {
        int c = tid + it * 256;
        int row = c >> 5, half = (c >> 4) & 1, ci = c & 15;
        uint4 v = half ? x4[(node0 + row) * 16 + ci]
                       : mean4[(node0 + row) * 16 + ci];
        *(uint4*)&sA[row][half * 128 + ci * 8] = v;
    }
    __syncthreads();

    const int wave = tid >> 6, lane = tid & 63;
    const int col = lane & 15, quad = lane >> 4;

    // ---- phase A: h = relu(A @ W1^T + bl1), N=256, K=256 ----
    floatx4 acc[2][4];
    const floatx4 zero = {0.f, 0.f, 0.f, 0.f};
#pragma unroll
    for (int mt = 0; mt < 2; mt++)
#pragma unroll
        for (int nt = 0; nt < 4; nt++) acc[mt][nt] = zero;

    const short8* w1base = (const short8*)W1s + wave * 2048 + lane;
#pragma unroll
    for (int ks = 0; ks < 8; ks++) {
        short8 a0 = *(const short8*)&sA[col][ks * 32 + quad * 8];
        short8 a1 = *(const short8*)&sA[16 + col][ks * 32 + quad * 8];
#pragma unroll
        for (int nt = 0; nt < 4; nt++) {
            short8 b = w1base[(nt * 8 + ks) * 64];
            acc[0][nt] = MFMA16(a0, b, acc[0][nt]);
            acc[1][nt] = MFMA16(a1, b, acc[1][nt]);
        }
    }

#pragma unroll
    for (int nt = 0; nt < 4; nt++) {
        int out = (wave * 4 + nt) * 16 + col;
        float bias = bl1[out];
#pragma unroll
        for (int mt = 0; mt < 2; mt++)
#pragma unroll
            for (int r = 0; r < 4; r++)
                sH[mt * 16 + quad * 4 + r][out] = f2bf(fmaxf(acc[mt][nt][r] + bias, 0.f));
    }
    __syncthreads();

    // ---- phase B: [z2|r2] = h @ W2^T, N=128, K=256 ----
    floatx4 acc2[2][2];
#pragma unroll
    for (int mt = 0; mt < 2; mt++)
#pragma unroll
        for (int nt = 0; nt < 2; nt++) acc2[mt][nt] = zero;

    const short8* w2base = (const short8*)W2s + wave * 1024 + lane;
#pragma unroll
    for (int ks = 0; ks < 8; ks++) {
        short8 h0 = *(const short8*)&sH[col][ks * 32 + quad * 8];
        short8 h1 = *(const short8*)&sH[16 + col][ks * 32 + quad * 8];
#pragma unroll
        for (int nt = 0; nt < 2; nt++) {
            short8 b = w2base[(nt * 8 + ks) * 64];
            acc2[0][nt] = MFMA16(h0, b, acc2[0][nt]);
            acc2[1][nt] = MFMA16(h1, b, acc2[1][nt]);
        }
    }

#pragma unroll
    for (int nt = 0; nt < 2; nt++) {
        int out = (wave * 2 + nt) * 16 + col;
#pragma unroll
        for (int mt = 0; mt < 2; mt++)
#pragma unroll
            for (int r = 0; r < 4; r++) {
                int node = node0 + mt * 16 + quad * 4 + r;
                float v = acc2[mt][nt][r];
                if (out < 64) z2bf[node * 64 + out] = f2bf(v);
                else          embOut[node * 64 + (out - 64)] = v;
            }
    }
}

// ---------------- gather: emb = agg(z2)/deg + bl2 + r2 ----------------
// one wave per node, EIGHTH-WAVE per edge: 8 lanes x uint4 = 128B z2 row.
// 8 edges per load instruction, 16 edges in flight per main iteration.
__global__ __launch_bounds__(256) void gather_emb(
        const uint4* __restrict__ z4, const int* __restrict__ srcS,
        const int* __restrict__ offs, const int* __restrict__ degI,
        const float* __restrict__ bl2, float* __restrict__ emb,
        uint4* __restrict__ emb4) {
    const int wave = threadIdx.x >> 6, lane = threadIdx.x & 63;
    const int n = blockIdx.x * 4 + wave;
    if (n >= N_NODES) return;
    const int start = offs[n], cnt = degI[n];
    const int* sp = srcS + start;
    const int o8 = lane >> 3, l8 = lane & 7;
    float s0 = 0.f, s1 = 0.f, s2 = 0.f, s3 = 0.f;
    float s4 = 0.f, s5 = 0.f, s6 = 0.f, s7 = 0.f;
    int j = 0;
    for (; j + 16 <= cnt; j += 16) {
        int i0 = sp[j + o8], i1 = sp[j + 8 + o8];
        uint4 v0 = z4[i0 * 8 + l8];
        uint4 v1 = z4[i1 * 8 + l8];
        ACC8(v0); ACC8(v1);
    }
    for (; j + 8 <= cnt; j += 8) {
        uint4 v = z4[sp[j + o8] * 8 + l8];
        ACC8(v);
    }
    if (o8 < cnt - j) {
        uint4 v = z4[sp[j + o8] * 8 + l8];
        ACC8(v);
    }
    // cross-eighth reduction: lanes 0-7 end with full sums
    s0 += __shfl_down(s0, 32); s1 += __shfl_down(s1, 32);
    s2 += __shfl_down(s2, 32); s3 += __shfl_down(s3, 32);
    s4 += __shfl_down(s4, 32); s5 += __shfl_down(s5, 32);
    s6 += __shfl_down(s6, 32); s7 += __shfl_down(s7, 32);
    s0 += __shfl_down(s0, 16); s1 += __shfl_down(s1, 16);
    s2 += __shfl_down(s2, 16); s3 += __shfl_down(s3, 16);
    s4 += __shfl_down(s4, 16); s5 += __shfl_down(s5, 16);
    s6 += __shfl_down(s6, 16); s7 += __shfl_down(s7, 16);
    s0 += __shfl_down(s0, 8);  s1 += __shfl_down(s1, 8);
    s2 += __shfl_down(s2, 8);  s3 += __shfl_down(s3, 8);
    s4 += __shfl_down(s4, 8);  s5 += __shfl_down(s5, 8);
    s6 += __shfl_down(s6, 8);  s7 += __shfl_down(s7, 8);
    if (lane < 8) {
        float rd = 1.0f / fmaxf((float)cnt, 1.0f);
        float4 ra = *(const float4*)&emb[n * 64 + l8 * 8];
        float4 rb = *(const float4*)&emb[n * 64 + l8 * 8 + 4];
        float4 ba = *(const float4*)&bl2[l8 * 8];
        float4 bb = *(const float4*)&bl2[l8 * 8 + 4];
        float e0 = s0 * rd + ba.x + ra.x;
        float e1 = s1 * rd + ba.y + ra.y;
        float e2 = s2 * rd + ba.z + ra.z;
        float e3 = s3 * rd + ba.w + ra.w;
        float e4 = s4 * rd + bb.x + rb.x;
        float e5 = s5 * rd + bb.y + rb.y;
        float e6 = s6 * rd + bb.z + rb.z;
        float e7 = s7 * rd + bb.w + rb.w;
        float4 wa = {e0, e1, e2, e3};
        float4 wb = {e4, e5, e6, e7};
        *(float4*)&emb[n * 64 + l8 * 8] = wa;
        *(float4*)&emb[n * 64 + l8 * 8 + 4] = wb;
        uint4 o;
        o.x = f2bf2(e0, e1);
        o.y = f2bf2(e2, e3);
        o.z = f2bf2(e4, e5);
        o.w = f2bf2(e6, e7);
        emb4[n * 8 + l8] = o;
    }
}

// ---------------- decoder MFMA: emb -> hid -> recon ----------------
__global__ __launch_bounds__(256, 4) void decoder_mfma(
        const unsigned* __restrict__ embbf,
        const unsigned short* __restrict__ F1s, const float* __restrict__ fc1b,
        const unsigned short* __restrict__ F2s, const float* __restrict__ fc2b,
        float* __restrict__ recon) {
    __shared__ unsigned short sE[MT][72];
    __shared__ unsigned short sH[MT][264];
    const int tid = threadIdx.x;
    const int node0 = blockIdx.x * MT;

    {
        const uint4* e4 = (const uint4*)embbf;
        int row = tid >> 3, ci = tid & 7;
        *(uint4*)&sE[row][ci * 8] = e4[(node0 + row) * 8 + ci];
    }
    __syncthreads();

    const int wave = tid >> 6, lane = tid & 63;
    const int col = lane & 15, quad = lane >> 4;

    // ---- phase A: hid = relu(emb @ fc1^T + fc1b), N=256, K=64 ----
    floatx4 acc[2][4];
    const floatx4 zero = {0.f, 0.f, 0.f, 0.f};
#pragma unroll
    for (int mt = 0; mt < 2; mt++)
#pragma unroll
        for (int nt = 0; nt < 4; nt++) acc[mt][nt] = zero;

    const short8* f1base = (const short8*)F1s + wave * 512 + lane;
#pragma unroll
    for (int ks = 0; ks < 2; ks++) {
        short8 a0 = *(const short8*)&sE[col][ks * 32 + quad * 8];
        short8 a1 = *(const short8*)&sE[16 + col][ks * 32 + quad * 8];
#pragma unroll
        for (int nt = 0; nt < 4; nt++) {
            short8 b = f1base[(nt * 2 + ks) * 64];
            acc[0][nt] = MFMA16(a0, b, acc[0][nt]);
            acc[1][nt] = MFMA16(a1, b, acc[1][nt]);
        }
    }

#pragma unroll
    for (int nt = 0; nt < 4; nt++) {
        int out = (wave * 4 + nt) * 16 + col;
        float bias = fc1b[out];
#pragma unroll
        for (int mt = 0; mt < 2; mt++)
#pragma unroll
            for (int r = 0; r < 4; r++)
                sH[mt * 16 + quad * 4 + r][out] = f2bf(fmaxf(acc[mt][nt][r] + bias, 0.f));
    }
    __syncthreads();

    // ---- phase B: recon = hid @ fc2^T + fc2b, N=128, K=256 ----
    floatx4 acc2[2][2];
#pragma unroll
    for (int mt = 0; mt < 2; mt++)
#pragma unroll
        for (int nt = 0; nt < 2; nt++) acc2[mt][nt] = zero;

    const short8* f2base = (const short8*)F2s + wave * 1024 + lane;
#pragma unroll
    for (int ks = 0; ks < 8; ks++) {
        short8 h0 = *(const short8*)&sH[col][ks * 32 + quad * 8];
        short8 h1 = *(const short8*)&sH[16 + col][ks * 32 + quad * 8];
#pragma unroll
        for (int nt = 0; nt < 2; nt++) {
            short8 b = f2base[(nt * 8 + ks) * 64];
            acc2[0][nt] = MFMA16(h0, b, acc2[0][nt]);
            acc2[1][nt] = MFMA16(h1, b, acc2[1][nt]);
        }
    }

#pragma unroll
    for (int nt = 0; nt < 2; nt++) {
        int out = (wave * 2 + nt) * 16 + col;
        float bias = fc2b[out];
#pragma unroll
        for (int mt = 0; mt < 2; mt++)
#pragma unroll
            for (int r = 0; r < 4; r++) {
                int node = node0 + mt * 16 + quad * 4 + r;
                recon[node * 128 + out] = acc2[mt][nt][r] + bias;
            }
    }
}

extern "C" void kernel_launch(void* const* d_in, const int* in_sizes, int n_in,
                              void* d_out, int out_size, void* d_ws, size_t ws_size,
                              hipStream_t stream) {
    const float* x    = (const float*)d_in[0];
    const int*   ei   = (const int*)d_in[1];
    const int E = in_sizes[1] / 2;
    const int* src = ei;
    const int* dst = ei + E;
    const float* Wl1  = (const float*)d_in[2];
    const float* bl1  = (const float*)d_in[3];
    const float* Wr1  = (const float*)d_in[4];
    const float* Wl2  = (const float*)d_in[5];
    const float* bl2  = (const float*)d_in[6];
    const float* Wr2  = (const float*)d_in[7];
    const float* fc1W = (const float*)d_in[8];
    const float* fc1b = (const float*)d_in[9];
    const float* fc2W = (const float*)d_in[10];
    const float* fc2b = (const float*)d_in[11];

    float* out   = (float*)d_out;
    float* emb   = out;                           // N*64
    float* recon = out + (size_t)N_NODES * D_E;   // N*128

    // workspace layout (512-aligned offsets)
    char* ws = (char*)d_ws;
    unsigned short* xbf    = (unsigned short*)(ws);             // 25,600,000 B
    unsigned*       meanbf = (unsigned*)(ws + 25600000);        // 25,600,000 B
    unsigned short* z2bf   = (unsigned short*)(ws + 51200000);  // 12,800,000 B
    unsigned*       embbf  = (unsigned*)(ws + 64000000);        // 12,800,000 B
    int* degI   = (int*)(ws + 76800000);                        //    400,000 B
    int* offs   = (int*)(ws + 77200384);                        //    400,000 B
    int* gcur      = (int*)(ws + 77600768);                     // 196*64 B padded counters
    int* bucketCnt = (int*)(ws + 77617152);                     // 196*64 B padded counters
    int* bucketOffs= (int*)(ws + 77633536);                     // 197*4 B
    int* srcS   = (int*)(ws + 78001664);                        //  6,400,000 B
    unsigned short* W1s = (unsigned short*)(ws + 84401664);     //    131,072 B
    unsigned short* W2s = (unsigned short*)(ws + 84532736);     //     65,536 B
    unsigned short* F1s = (unsigned short*)(ws + 84598272);     //     32,768 B
    unsigned short* F2s = (unsigned short*)(ws + 84631040);     //     65,536 B
    // end 84,696,576 B
    // pairs buffer (6.4MB) reuses the meanbf region: its lifetime ends before
    // gather_mean_bf writes meanbf.
    unsigned* pairs = (unsigned*)(ws + 25600000);

    // gcur + bucketCnt are contiguous: one memset
    hipMemsetAsync(gcur, 0, 32768, stream);

    convert_weights<<<(147456 + 255) / 256, 256, 0, stream>>>(
        Wl1, Wr1, Wl2, Wr2, fc1W, fc2W, W1s, W2s, F1s, F2s);
    convert_x<<<(N_NODES * 32 + 255) / 256, 256, 0, stream>>>(
        (const float4*)x, (uint2*)xbf, N_NODES * 32);

    // counting sort of edges by dst (bucket hist + radix two-pass)
    const int nChunks = (E + CHUNK - 1) / CHUNK;  // 196 at E=1.6M
    bucket_hist<<<nChunks, RCR_T, 0, stream>>>(dst, bucketCnt, E);
    bucket_scan<<<1, 256, 0, stream>>>(bucketCnt, bucketOffs);
    radix_count_reserve<<<nChunks, RCR_T, 0, stream>>>(
        src, dst, bucketOffs, gcur, pairs, E);
    radix_scatter2<<<NBUCK, 512, 0, stream>>>(
        pairs, bucketOffs, degI, offs, srcS);

    // layer 1
    gather_mean_bf<<<(N_NODES + 3) / 4, 256, 0, stream>>>(
        (const uint4*)xbf, srcS, offs, degI, (uint4*)meanbf);
    layer1_mfma<<<N_NODES / MT, 256, 0, stream>>>(
        (const unsigned*)xbf, meanbf, W1s, bl1, W2s, z2bf, emb);

    // layer 2 aggregation + emb finalize
    gather_emb<<<(N_NODES + 3) / 4, 256, 0, stream>>>(
        (const uint4*)z2bf, srcS, offs, degI, bl2, emb, (uint4*)embbf);

    // decoder
    decoder_mfma<<<N_NODES / MT, 256, 0, stream>>>(
        embbf, F1s, fc1b, F2s, fc2b, recon);
}